// Round 8
// baseline (142.700 us; speedup 1.0000x reference)
//
#include <hip/hip_runtime.h>

#define B 8
#define N 512
#define D 128
#define H 128
#define IC 32     // i-rows per block (pair kernel)
#define JT 64     // j-cols per block (4 waves x 16)

typedef __attribute__((ext_vector_type(8))) _Float16 f16x8;
typedef __attribute__((ext_vector_type(4))) float f32x4;

union F8 { uint4 u; f16x8 f; };

// ---------------- kernel 0: build Wpq (f16), W2h (f16), b1e (f32) ----------------
__global__ void build_w_kernel(const float* __restrict__ W1,
                               const float* __restrict__ W2,
                               const float* __restrict__ b1,
                               _Float16* __restrict__ Wpq,
                               _Float16* __restrict__ W2h,
                               float* __restrict__ b1e) {
    int t = blockIdx.x * blockDim.x + threadIdx.x;   // 0 .. 16383
    if (t < H * D) {
        int h = t >> 7, k = t & 127;
        float wa = W1[h * 384 + k];
        float wb = W1[h * 384 + 128 + k];
        float wc = W1[h * 384 + 256 + k];
        Wpq[h * 128 + k]         = (_Float16)(wa + wc);
        Wpq[(128 + h) * 128 + k] = (_Float16)(wb - wc);
    }
    if (t < 64 * H) W2h[t] = (_Float16)W2[t];
    if (t < 256)    b1e[t] = (t < 128) ? b1[t] : 0.f;
}

// ---------------- kernel 1: PQ = f16( F0 @ Wpq^T + b1e ) via f16 MFMA ----------------
__global__ __launch_bounds__(64) void pq_mfma_kernel(const float* __restrict__ F0,
                                                     const _Float16* __restrict__ Wpq,
                                                     const float* __restrict__ b1e,
                                                     _Float16* __restrict__ PQ) {
    int r0 = blockIdx.x * 16;        // F0 row base
    int cb = blockIdx.y * 64;        // output col base
    int lane = threadIdx.x;
    int lp = lane & 15, lg = lane >> 4;

    f16x8 af[4];
    const float* fr = F0 + (size_t)(r0 + lp) * D;
#pragma unroll
    for (int ks = 0; ks < 4; ++ks) {
        float4 a0 = *(const float4*)(fr + ks * 32 + lg * 8);
        float4 a1 = *(const float4*)(fr + ks * 32 + lg * 8 + 4);
        f16x8 v;
        v[0] = (_Float16)a0.x; v[1] = (_Float16)a0.y;
        v[2] = (_Float16)a0.z; v[3] = (_Float16)a0.w;
        v[4] = (_Float16)a1.x; v[5] = (_Float16)a1.y;
        v[6] = (_Float16)a1.z; v[7] = (_Float16)a1.w;
        af[ks] = v;
    }

#pragma unroll
    for (int ct = 0; ct < 4; ++ct) {
        int col = cb + ct * 16 + lp;
        const _Float16* wrow = Wpq + (size_t)col * 128;
        f32x4 acc = 0.f;
#pragma unroll
        for (int ks = 0; ks < 4; ++ks) {
            f16x8 bf = *(const f16x8*)(wrow + ks * 32 + lg * 8);
            acc = __builtin_amdgcn_mfma_f32_16x16x32_f16(af[ks], bf, acc, 0, 0, 0);
        }
        float b1v = b1e[col];
#pragma unroll
        for (int e = 0; e < 4; ++e) {
            int row = r0 + lg * 4 + e;
            PQ[(size_t)row * 256 + col] = (_Float16)(acc[e] + b1v);
        }
    }
}

// ---------------- kernel 2: fused pair MLP, f16 MFMA, ii-unroll x2 ----------------
// launch_bounds(256,4): force combined VGPR+AGPR <= 128/wave -> 4 waves/SIMD,
// so all 1024 blocks (4/CU) are co-resident. Static need ~120 regs -> no spill.
__global__ __launch_bounds__(256, 4) void pair_mfma_kernel(
        const _Float16* __restrict__ PQ,
        const _Float16* __restrict__ W2h,
        const float* __restrict__ b2, const float* __restrict__ W3,
        const float* __restrict__ b3v, const int* __restrict__ mask,
        float* __restrict__ out) {
    int b  = blockIdx.z;
    int i0 = blockIdx.y * IC;
    int j0 = blockIdx.x * JT;
    int tid  = threadIdx.x;
    int lane = tid & 63;
    int w    = tid >> 6;          // wave 0..3
    int lg   = lane >> 4;         // k-slice group 0..3
    int lp   = lane & 15;         // pair col / o row-within-group

    __shared__ uint4 Pl[IC][16];  // P rows as f16: [row][16B chunk]
    __shared__ int   mI[IC];

    {
#pragma unroll
        for (int it = 0; it < 2; ++it) {
            int r = (tid >> 4) + it * 16;
            int c = tid & 15;
            Pl[r][c] = *(const uint4*)(PQ + ((size_t)(b * N) + i0 + r) * 256 + c * 8);
        }
        if (tid < IC) mI[tid] = mask[b * N + i0 + tid];
    }
    __syncthreads();

    // W2 fragments: w2f[g][c] = row o=g*16+lp, k = c*32 + lg*8 .. +7  (resident)
    F8 w2f[4][4];
#pragma unroll
    for (int g = 0; g < 4; ++g)
#pragma unroll
        for (int c = 0; c < 4; ++c)
            w2f[g][c].u = *(const uint4*)(W2h + (size_t)(g * 16 + lp) * 128 + c * 32 + lg * 8);

    // Q fragments: lane's pair j = j0 + w*16 + lp
    int j = j0 + w * 16 + lp;
    F8 qf[4];
    {
        const _Float16* qrow = PQ + ((size_t)(b * N) + j) * 256 + 128;
#pragma unroll
        for (int c = 0; c < 4; ++c)
            qf[c].u = *(const uint4*)(qrow + c * 32 + lg * 8);
    }

    // epilogue constants: lane's o indices = g*16 + lg*4 + {0..3}
    f32x4 b2v[4], w3v[4];
#pragma unroll
    for (int g = 0; g < 4; ++g) {
        b2v[g] = *(const f32x4*)(b2 + g * 16 + lg * 4);
        w3v[g] = *(const f32x4*)(W3 + g * 16 + lg * 4);
    }
    float b3s = b3v[0];
    int   mj  = mask[b * N + j];
    const f32x4 z4 = 0.f;
    const f16x8 zh = (f16x8)(_Float16)0;

    size_t outrow = ((size_t)(b * N) + i0) * N + j0 + w * 16 + lp;

    for (int ii = 0; ii < IC; ii += 2) {
        f32x4 acc0[4], acc1[4];
#pragma unroll
        for (int g = 0; g < 4; ++g) { acc0[g] = 0.f; acc1[g] = 0.f; }

#pragma unroll
        for (int c = 0; c < 4; ++c) {
            F8 ph0, ph1;
            ph0.u = Pl[ii][c * 4 + lg];
            ph1.u = Pl[ii + 1][c * 4 + lg];
            f16x8 hv0 = __builtin_elementwise_max(ph0.f + qf[c].f, zh);
            f16x8 hv1 = __builtin_elementwise_max(ph1.f + qf[c].f, zh);
#pragma unroll
            for (int g = 0; g < 4; ++g) {
                acc0[g] = __builtin_amdgcn_mfma_f32_16x16x32_f16(w2f[g][c].f, hv0,
                                                                 acc0[g], 0, 0, 0);
                acc1[g] = __builtin_amdgcn_mfma_f32_16x16x32_f16(w2f[g][c].f, hv1,
                                                                 acc1[g], 0, 0, 0);
            }
        }

        // packed-f32 epilogue for both i's
        f32x4 lr40 = 0.f, lr41 = 0.f;
#pragma unroll
        for (int g = 0; g < 4; ++g) {
            f32x4 t0 = __builtin_elementwise_max(acc0[g] + b2v[g], z4);
            f32x4 t1 = __builtin_elementwise_max(acc1[g] + b2v[g], z4);
            lr40 = __builtin_elementwise_fma(t0, w3v[g], lr40);
            lr41 = __builtin_elementwise_fma(t1, w3v[g], lr41);
        }
        float lr0 = (lr40.x + lr40.y) + (lr40.z + lr40.w);
        float lr1 = (lr41.x + lr41.y) + (lr41.z + lr41.w);
        lr0 += __shfl_xor(lr0, 16);
        lr0 += __shfl_xor(lr0, 32);
        lr1 += __shfl_xor(lr1, 16);
        lr1 += __shfl_xor(lr1, 32);

        float logit0 = lr0 + b3s;
        float logit1 = lr1 + b3s;
        bool  m0 = (mI[ii] != 0)     && (mj != 0);
        bool  m1 = (mI[ii + 1] != 0) && (mj != 0);
        float v0 = m0 ? 1.f / (1.f + __expf(-logit0)) : 0.f;
        float v1 = m1 ? 1.f / (1.f + __expf(-logit1)) : 0.f;

        if (lane < 16) {
            out[outrow + (size_t)ii * N]       = v0;
            out[outrow + (size_t)(ii + 1) * N] = v1;
        }
    }
}

extern "C" void kernel_launch(void* const* d_in, const int* in_sizes, int n_in,
                              void* d_out, int out_size, void* d_ws, size_t ws_size,
                              hipStream_t stream) {
    const float* F0  = (const float*)d_in[0];
    const int*   msk = (const int*)  d_in[1];
    const float* W1  = (const float*)d_in[2];
    const float* b1  = (const float*)d_in[3];
    const float* W2  = (const float*)d_in[4];
    const float* b2  = (const float*)d_in[5];
    const float* W3  = (const float*)d_in[6];
    const float* b3  = (const float*)d_in[7];
    float* out = (float*)d_out;

    char* ws = (char*)d_ws;
    _Float16* PQ  = (_Float16*)ws;                    // 2 MB
    _Float16* Wpq = (_Float16*)(ws + (2u << 20));     // 64 KB
    _Float16* W2h = (_Float16*)(ws + (2u << 20) + (64u << 10));  // 16 KB
    float*    b1e = (float*)   (ws + (2u << 20) + (80u << 10));  // 1 KB

    build_w_kernel<<<64, 256, 0, stream>>>(W1, W2, b1, Wpq, W2h, b1e);
    pq_mfma_kernel<<<dim3(B * N / 16, 4), 64, 0, stream>>>(F0, Wpq, b1e, PQ);
    pair_mfma_kernel<<<dim3(N / JT, N / IC, B), 256, 0, stream>>>(
        PQ, W2h, b2, W3, b3, msk, out);
}

// Round 9
// 58.431 us; speedup vs baseline: 2.4422x; 2.4422x over previous
//
#include <hip/hip_runtime.h>

#define B 8
#define N 512
#define D 128
#define H 128
#define IC 32     // i-rows per block (pair kernel)
#define JT 64     // j-cols per block (4 waves x 16)

typedef __attribute__((ext_vector_type(8))) _Float16 f16x8;
typedef __attribute__((ext_vector_type(4))) float f32x4;

union F8 { uint4 u; f16x8 f; };

// ---------------- kernel 0: build Wpq (f16), W2h (f16), b1e (f32) ----------------
__global__ void build_w_kernel(const float* __restrict__ W1,
                               const float* __restrict__ W2,
                               const float* __restrict__ b1,
                               _Float16* __restrict__ Wpq,
                               _Float16* __restrict__ W2h,
                               float* __restrict__ b1e) {
    int t = blockIdx.x * blockDim.x + threadIdx.x;   // 0 .. 16383
    if (t < H * D) {
        int h = t >> 7, k = t & 127;
        float wa = W1[h * 384 + k];
        float wb = W1[h * 384 + 128 + k];
        float wc = W1[h * 384 + 256 + k];
        Wpq[h * 128 + k]         = (_Float16)(wa + wc);
        Wpq[(128 + h) * 128 + k] = (_Float16)(wb - wc);
    }
    if (t < 64 * H) W2h[t] = (_Float16)W2[t];
    if (t < 256)    b1e[t] = (t < 128) ? b1[t] : 0.f;
}

// ---------------- kernel 1: PQ = f16( F0 @ Wpq^T + b1e ) via f16 MFMA ----------------
__global__ __launch_bounds__(64) void pq_mfma_kernel(const float* __restrict__ F0,
                                                     const _Float16* __restrict__ Wpq,
                                                     const float* __restrict__ b1e,
                                                     _Float16* __restrict__ PQ) {
    int r0 = blockIdx.x * 16;        // F0 row base
    int cb = blockIdx.y * 64;        // output col base
    int lane = threadIdx.x;
    int lp = lane & 15, lg = lane >> 4;

    f16x8 af[4];
    const float* fr = F0 + (size_t)(r0 + lp) * D;
#pragma unroll
    for (int ks = 0; ks < 4; ++ks) {
        float4 a0 = *(const float4*)(fr + ks * 32 + lg * 8);
        float4 a1 = *(const float4*)(fr + ks * 32 + lg * 8 + 4);
        f16x8 v;
        v[0] = (_Float16)a0.x; v[1] = (_Float16)a0.y;
        v[2] = (_Float16)a0.z; v[3] = (_Float16)a0.w;
        v[4] = (_Float16)a1.x; v[5] = (_Float16)a1.y;
        v[6] = (_Float16)a1.z; v[7] = (_Float16)a1.w;
        af[ks] = v;
    }

#pragma unroll
    for (int ct = 0; ct < 4; ++ct) {
        int col = cb + ct * 16 + lp;
        const _Float16* wrow = Wpq + (size_t)col * 128;
        f32x4 acc = 0.f;
#pragma unroll
        for (int ks = 0; ks < 4; ++ks) {
            f16x8 bf = *(const f16x8*)(wrow + ks * 32 + lg * 8);
            acc = __builtin_amdgcn_mfma_f32_16x16x32_f16(af[ks], bf, acc, 0, 0, 0);
        }
        float b1v = b1e[col];
#pragma unroll
        for (int e = 0; e < 4; ++e) {
            int row = r0 + lg * 4 + e;
            PQ[(size_t)row * 256 + col] = (_Float16)(acc[e] + b1v);
        }
    }
}

// ---------------- kernel 2: fused pair MLP; 2-stage acc pipeline ----------------
// epilogue(i-1) runs while MFMA cluster(i) is in flight (separate pipes).
__global__ __launch_bounds__(256) void pair_mfma_kernel(
        const _Float16* __restrict__ PQ,
        const _Float16* __restrict__ W2h,
        const float* __restrict__ b2, const float* __restrict__ W3,
        const float* __restrict__ b3v, const int* __restrict__ mask,
        float* __restrict__ out) {
    int b  = blockIdx.z;
    int i0 = blockIdx.y * IC;
    int j0 = blockIdx.x * JT;
    int tid  = threadIdx.x;
    int lane = tid & 63;
    int w    = tid >> 6;          // wave 0..3
    int lg   = lane >> 4;         // k-slice group 0..3
    int lp   = lane & 15;         // pair col / o row-within-group

    __shared__ uint4 Pl[IC][16];  // P rows as f16: [row][16B chunk]
    __shared__ int   mI[IC];

    {
#pragma unroll
        for (int it = 0; it < 2; ++it) {
            int r = (tid >> 4) + it * 16;
            int c = tid & 15;
            Pl[r][c] = *(const uint4*)(PQ + ((size_t)(b * N) + i0 + r) * 256 + c * 8);
        }
        if (tid < IC) mI[tid] = mask[b * N + i0 + tid];
    }
    __syncthreads();

    // W2 fragments: w2f[g][c] = row o=g*16+lp, k = c*32 + lg*8 .. +7  (resident)
    F8 w2f[4][4];
#pragma unroll
    for (int g = 0; g < 4; ++g)
#pragma unroll
        for (int c = 0; c < 4; ++c)
            w2f[g][c].u = *(const uint4*)(W2h + (size_t)(g * 16 + lp) * 128 + c * 32 + lg * 8);

    // Q fragments: lane's pair j = j0 + w*16 + lp
    int j = j0 + w * 16 + lp;
    F8 qf[4];
    {
        const _Float16* qrow = PQ + ((size_t)(b * N) + j) * 256 + 128;
#pragma unroll
        for (int c = 0; c < 4; ++c)
            qf[c].u = *(const uint4*)(qrow + c * 32 + lg * 8);
    }

    // epilogue constants: lane's o indices = g*16 + lg*4 + {0..3}
    f32x4 b2v[4], w3v[4];
#pragma unroll
    for (int g = 0; g < 4; ++g) {
        b2v[g] = *(const f32x4*)(b2 + g * 16 + lg * 4);
        w3v[g] = *(const f32x4*)(W3 + g * 16 + lg * 4);
    }
    float b3s = b3v[0];
    int   mj  = mask[b * N + j];
    const f32x4 z4 = 0.f;
    const f16x8 zh = (f16x8)(_Float16)0;

    size_t outrow = ((size_t)(b * N) + i0) * N + j0 + w * 16 + lp;

    f32x4 accA[4], accB[4];

    // ---- stage macros (static indexing; named buffers per rule #20) ----
#define MFMA_STAGE(ACC, II)                                                    \
    {                                                                          \
        _Pragma("unroll")                                                      \
        for (int g = 0; g < 4; ++g) ACC[g] = 0.f;                              \
        __builtin_amdgcn_s_setprio(1);                                         \
        _Pragma("unroll")                                                      \
        for (int c = 0; c < 4; ++c) {                                          \
            F8 ph; ph.u = Pl[II][c * 4 + lg];                                  \
            f16x8 hv = __builtin_elementwise_max(ph.f + qf[c].f, zh);          \
            _Pragma("unroll")                                                  \
            for (int g = 0; g < 4; ++g)                                        \
                ACC[g] = __builtin_amdgcn_mfma_f32_16x16x32_f16(               \
                    w2f[g][c].f, hv, ACC[g], 0, 0, 0);                         \
        }                                                                      \
        __builtin_amdgcn_s_setprio(0);                                         \
    }

#define EPI_STAGE(ACC, II)                                                     \
    {                                                                          \
        f32x4 lr4 = 0.f;                                                       \
        _Pragma("unroll")                                                      \
        for (int g = 0; g < 4; ++g) {                                          \
            f32x4 t = __builtin_elementwise_max(ACC[g] + b2v[g], z4);          \
            lr4 = __builtin_elementwise_fma(t, w3v[g], lr4);                   \
        }                                                                      \
        float lr = (lr4.x + lr4.y) + (lr4.z + lr4.w);                          \
        lr += __shfl_xor(lr, 16);                                              \
        lr += __shfl_xor(lr, 32);                                              \
        float logit = lr + b3s;                                                \
        bool  m     = (mI[II] != 0) && (mj != 0);                              \
        float val   = m ? 1.f / (1.f + __expf(-logit)) : 0.f;                  \
        if (lane < 16) out[outrow + (size_t)(II) * N] = val;                   \
    }

    // ---- 2-stage pipeline: epilogue(i-1) overlaps MFMA(i) ----
    MFMA_STAGE(accA, 0)
#pragma unroll 1
    for (int ii = 0; ii + 2 < IC; ii += 2) {
        MFMA_STAGE(accB, ii + 1)
        EPI_STAGE(accA, ii)
        MFMA_STAGE(accA, ii + 2)
        EPI_STAGE(accB, ii + 1)
    }
    MFMA_STAGE(accB, IC - 1)
    EPI_STAGE(accA, IC - 2)
    EPI_STAGE(accB, IC - 1)

#undef MFMA_STAGE
#undef EPI_STAGE
}

extern "C" void kernel_launch(void* const* d_in, const int* in_sizes, int n_in,
                              void* d_out, int out_size, void* d_ws, size_t ws_size,
                              hipStream_t stream) {
    const float* F0  = (const float*)d_in[0];
    const int*   msk = (const int*)  d_in[1];
    const float* W1  = (const float*)d_in[2];
    const float* b1  = (const float*)d_in[3];
    const float* W2  = (const float*)d_in[4];
    const float* b2  = (const float*)d_in[5];
    const float* W3  = (const float*)d_in[6];
    const float* b3  = (const float*)d_in[7];
    float* out = (float*)d_out;

    char* ws = (char*)d_ws;
    _Float16* PQ  = (_Float16*)ws;                    // 2 MB
    _Float16* Wpq = (_Float16*)(ws + (2u << 20));     // 64 KB
    _Float16* W2h = (_Float16*)(ws + (2u << 20) + (64u << 10));  // 16 KB
    float*    b1e = (float*)   (ws + (2u << 20) + (80u << 10));  // 1 KB

    build_w_kernel<<<64, 256, 0, stream>>>(W1, W2, b1, Wpq, W2h, b1e);
    pq_mfma_kernel<<<dim3(B * N / 16, 4), 64, 0, stream>>>(F0, Wpq, b1e, PQ);
    pair_mfma_kernel<<<dim3(N / JT, N / IC, B), 256, 0, stream>>>(
        PQ, W2h, b2, W3, b3, msk, out);
}

// Round 10
// 57.518 us; speedup vs baseline: 2.4810x; 1.0159x over previous
//
#include <hip/hip_runtime.h>

#define B 8
#define N 512
#define D 128
#define H 128
#define IC 32     // i-rows per block (pair kernel)
#define JT 64     // j-cols per block (4 waves x 16)

typedef __attribute__((ext_vector_type(8))) _Float16 f16x8;
typedef __attribute__((ext_vector_type(4))) float f32x4;

union F8 { uint4 u; f16x8 f; };

// W2-row permutation: MFMA g, row m holds actual output o = pi(g,m)
// pi(g,m) = (g>=2)*32 + (m>>2)*8 + (g&1)*4 + (m&3)
// => after epilogue, lane-group lg holds o = lg*8+e (e=0..7) per 32-o half,
//    which is exactly the B-fragment k-slot layout for the reduce-MFMA.
__device__ __host__ inline int w2perm(int g, int m) {
    return ((g >> 1) << 5) + ((m >> 2) << 3) + ((g & 1) << 2) + (m & 3);
}

// ---------------- kernel 0: build Wpq (f16), permuted W2h/b2p, w3h, b1e ----------------
__global__ void build_w_kernel(const float* __restrict__ W1,
                               const float* __restrict__ W2,
                               const float* __restrict__ b1,
                               const float* __restrict__ b2,
                               const float* __restrict__ W3,
                               _Float16* __restrict__ Wpq,
                               _Float16* __restrict__ W2h,
                               float* __restrict__ b1e,
                               float* __restrict__ b2p,
                               _Float16* __restrict__ w3h) {
    int t = blockIdx.x * blockDim.x + threadIdx.x;   // 0 .. 16383
    if (t < H * D) {
        int h = t >> 7, k = t & 127;
        float wa = W1[h * 384 + k];
        float wb = W1[h * 384 + 128 + k];
        float wc = W1[h * 384 + 256 + k];
        Wpq[h * 128 + k]         = (_Float16)(wa + wc);
        Wpq[(128 + h) * 128 + k] = (_Float16)(wb - wc);
    }
    if (t < 64 * H) {   // permuted W2 rows
        int on = t >> 7, k = t & 127;
        int pi = w2perm(on >> 4, on & 15);
        W2h[t] = (_Float16)W2[pi * 128 + k];
    }
    if (t < 256) b1e[t] = (t < 128) ? b1[t] : 0.f;
    if (t < 64) {
        int pi = w2perm(t >> 4, t & 15);
        b2p[t] = b2[pi];
        w3h[t] = (_Float16)W3[t];   // original order (k == o in reduce-MFMA)
    }
}

// ---------------- kernel 1: PQ = f16( F0 @ Wpq^T + b1e ) via f16 MFMA ----------------
__global__ __launch_bounds__(64) void pq_mfma_kernel(const float* __restrict__ F0,
                                                     const _Float16* __restrict__ Wpq,
                                                     const float* __restrict__ b1e,
                                                     _Float16* __restrict__ PQ) {
    int r0 = blockIdx.x * 16;        // F0 row base
    int cb = blockIdx.y * 64;        // output col base
    int lane = threadIdx.x;
    int lp = lane & 15, lg = lane >> 4;

    f16x8 af[4];
    const float* fr = F0 + (size_t)(r0 + lp) * D;
#pragma unroll
    for (int ks = 0; ks < 4; ++ks) {
        float4 a0 = *(const float4*)(fr + ks * 32 + lg * 8);
        float4 a1 = *(const float4*)(fr + ks * 32 + lg * 8 + 4);
        f16x8 v;
        v[0] = (_Float16)a0.x; v[1] = (_Float16)a0.y;
        v[2] = (_Float16)a0.z; v[3] = (_Float16)a0.w;
        v[4] = (_Float16)a1.x; v[5] = (_Float16)a1.y;
        v[6] = (_Float16)a1.z; v[7] = (_Float16)a1.w;
        af[ks] = v;
    }

#pragma unroll
    for (int ct = 0; ct < 4; ++ct) {
        int col = cb + ct * 16 + lp;
        const _Float16* wrow = Wpq + (size_t)col * 128;
        f32x4 acc = 0.f;
#pragma unroll
        for (int ks = 0; ks < 4; ++ks) {
            f16x8 bf = *(const f16x8*)(wrow + ks * 32 + lg * 8);
            acc = __builtin_amdgcn_mfma_f32_16x16x32_f16(af[ks], bf, acc, 0, 0, 0);
        }
        float b1v = b1e[col];
#pragma unroll
        for (int e = 0; e < 4; ++e) {
            int row = r0 + lg * 4 + e;
            PQ[(size_t)row * 256 + col] = (_Float16)(acc[e] + b1v);
        }
    }
}

// ---------------- kernel 2: fused pair MLP; reduce-MFMA epilogue (no shfl) ----------------
__global__ __launch_bounds__(256) void pair_mfma_kernel(
        const _Float16* __restrict__ PQ,
        const _Float16* __restrict__ W2h,
        const float* __restrict__ b2p, const _Float16* __restrict__ w3h,
        const float* __restrict__ b3v, const int* __restrict__ mask,
        float* __restrict__ out) {
    int b  = blockIdx.z;
    int i0 = blockIdx.y * IC;
    int j0 = blockIdx.x * JT;
    int tid  = threadIdx.x;
    int lane = tid & 63;
    int w    = tid >> 6;          // wave 0..3
    int lg   = lane >> 4;         // k-slice group 0..3
    int lp   = lane & 15;         // pair col / row-within-group

    __shared__ uint4 Pl[IC][16];  // P rows as f16: [row][16B chunk]
    __shared__ int   mI[IC];

    {
#pragma unroll
        for (int it = 0; it < 2; ++it) {
            int r = (tid >> 4) + it * 16;
            int c = tid & 15;
            Pl[r][c] = *(const uint4*)(PQ + ((size_t)(b * N) + i0 + r) * 256 + c * 8);
        }
        if (tid < IC) mI[tid] = mask[b * N + i0 + tid];
    }
    __syncthreads();

    // W2 fragments (permuted rows): w2f[g][c] = A row lp of MFMA g, k = c*32+lg*8..+7
    F8 w2f[4][4];
#pragma unroll
    for (int g = 0; g < 4; ++g)
#pragma unroll
        for (int c = 0; c < 4; ++c)
            w2f[g][c].u = *(const uint4*)(W2h + (size_t)(g * 16 + lp) * 128 + c * 32 + lg * 8);

    // Q fragments: lane's pair j = j0 + w*16 + lp
    int j = j0 + w * 16 + lp;
    F8 qf[4];
    {
        const _Float16* qrow = PQ + ((size_t)(b * N) + j) * 256 + 128;
#pragma unroll
        for (int c = 0; c < 4; ++c)
            qf[c].u = *(const uint4*)(qrow + c * 32 + lg * 8);
    }

    // epilogue constants (permuted b2; W3 as reduce-MFMA A-fragments)
    f32x4 b2v[4];
#pragma unroll
    for (int g = 0; g < 4; ++g)
        b2v[g] = *(const f32x4*)(b2p + g * 16 + lg * 4);
    f16x8 w3f0 = *(const f16x8*)(w3h + lg * 8);        // o = lg*8+e
    f16x8 w3f1 = *(const f16x8*)(w3h + 32 + lg * 8);   // o = 32+lg*8+e
    float b3s = b3v[0];
    int   mj  = mask[b * N + j];
    const f32x4 z4 = 0.f;
    const f16x8 zh = (f16x8)(_Float16)0;

    size_t outrow = ((size_t)(b * N) + i0) * N + j0 + w * 16 + lp;

    f32x4 accA[4], accB[4];
    F8 phA[4], phB[4];

#define LOADPH(PH, II)                                                         \
    {                                                                          \
        _Pragma("unroll")                                                      \
        for (int c = 0; c < 4; ++c) PH[c].u = Pl[II][c * 4 + lg];              \
    }

#define COMPUTE(ACC, PH)                                                       \
    {                                                                          \
        _Pragma("unroll")                                                      \
        for (int g = 0; g < 4; ++g) ACC[g] = 0.f;                              \
        __builtin_amdgcn_s_setprio(1);                                         \
        _Pragma("unroll")                                                      \
        for (int c = 0; c < 4; ++c) {                                          \
            f16x8 hv = __builtin_elementwise_max(PH[c].f + qf[c].f, zh);       \
            _Pragma("unroll")                                                  \
            for (int g = 0; g < 4; ++g)                                        \
                ACC[g] = __builtin_amdgcn_mfma_f32_16x16x32_f16(               \
                    w2f[g][c].f, hv, ACC[g], 0, 0, 0);                         \
        }                                                                      \
        __builtin_amdgcn_s_setprio(0);                                         \
    }

// epilogue: t_g = relu(acc_g + b2_g) -> f16 B-frags (o = lg*8+e / 32+lg*8+e)
// logit = reduce-MFMA(W3, t) + b3; no cross-lane ops.
#define EPI(ACC, II)                                                           \
    {                                                                          \
        f32x4 t0 = __builtin_elementwise_max(ACC[0] + b2v[0], z4);             \
        f32x4 t1 = __builtin_elementwise_max(ACC[1] + b2v[1], z4);             \
        f32x4 t2 = __builtin_elementwise_max(ACC[2] + b2v[2], z4);             \
        f32x4 t3 = __builtin_elementwise_max(ACC[3] + b2v[3], z4);             \
        f16x8 h0, h1;                                                          \
        h0[0] = (_Float16)t0[0]; h0[1] = (_Float16)t0[1];                      \
        h0[2] = (_Float16)t0[2]; h0[3] = (_Float16)t0[3];                      \
        h0[4] = (_Float16)t1[0]; h0[5] = (_Float16)t1[1];                      \
        h0[6] = (_Float16)t1[2]; h0[7] = (_Float16)t1[3];                      \
        h1[0] = (_Float16)t2[0]; h1[1] = (_Float16)t2[1];                      \
        h1[2] = (_Float16)t2[2]; h1[3] = (_Float16)t2[3];                      \
        h1[4] = (_Float16)t3[0]; h1[5] = (_Float16)t3[1];                      \
        h1[6] = (_Float16)t3[2]; h1[7] = (_Float16)t3[3];                      \
        f32x4 rac = {b3s, b3s, b3s, b3s};                                      \
        rac = __builtin_amdgcn_mfma_f32_16x16x32_f16(w3f0, h0, rac, 0, 0, 0);  \
        rac = __builtin_amdgcn_mfma_f32_16x16x32_f16(w3f1, h1, rac, 0, 0, 0);  \
        bool  m   = (mI[II] != 0) && (mj != 0);                                \
        float val = m ? 1.f / (1.f + __expf(-rac[0])) : 0.f;                   \
        if (lane < 16) out[outrow + (size_t)(II) * N] = val;                   \
    }

    // ---- 3-stage modulo pipeline: LOAD(ii+2) || COMPUTE(ii+1) || EPI(ii) ----
    LOADPH(phA, 0)
    LOADPH(phB, 1)
    COMPUTE(accA, phA)
#pragma unroll 1
    for (int ii = 0; ii + 2 < IC; ii += 2) {
        LOADPH(phA, ii + 2)
        COMPUTE(accB, phB)
        EPI(accA, ii)
        LOADPH(phB, ii + 3)
        COMPUTE(accA, phA)
        EPI(accB, ii + 1)
    }
    COMPUTE(accB, phB)
    EPI(accA, IC - 2)
    EPI(accB, IC - 1)

#undef LOADPH
#undef COMPUTE
#undef EPI
}

extern "C" void kernel_launch(void* const* d_in, const int* in_sizes, int n_in,
                              void* d_out, int out_size, void* d_ws, size_t ws_size,
                              hipStream_t stream) {
    const float* F0  = (const float*)d_in[0];
    const int*   msk = (const int*)  d_in[1];
    const float* W1  = (const float*)d_in[2];
    const float* b1  = (const float*)d_in[3];
    const float* W2  = (const float*)d_in[4];
    const float* b2  = (const float*)d_in[5];
    const float* W3  = (const float*)d_in[6];
    const float* b3  = (const float*)d_in[7];
    float* out = (float*)d_out;

    char* ws = (char*)d_ws;
    _Float16* PQ  = (_Float16*)ws;                                   // 2 MB
    _Float16* Wpq = (_Float16*)(ws + (2u << 20));                    // 64 KB
    _Float16* W2h = (_Float16*)(ws + (2u << 20) + (64u << 10));      // 16 KB
    float*    b1e = (float*)   (ws + (2u << 20) + (80u << 10));      // 1 KB
    float*    b2p = (float*)   (ws + (2u << 20) + (81u << 10));      // 256 B
    _Float16* w3h = (_Float16*)(ws + (2u << 20) + (82u << 10));      // 128 B

    build_w_kernel<<<64, 256, 0, stream>>>(W1, W2, b1, b2, W3, Wpq, W2h, b1e, b2p, w3h);
    pq_mfma_kernel<<<dim3(B * N / 16, 4), 64, 0, stream>>>(F0, Wpq, b1e, PQ);
    pair_mfma_kernel<<<dim3(N / JT, N / IC, B), 256, 0, stream>>>(
        PQ, W2h, b2p, w3h, b3, msk, out);
}

// Round 11
// 52.377 us; speedup vs baseline: 2.7245x; 1.0982x over previous
//
#include <hip/hip_runtime.h>

#define B 8
#define N 512
#define D 128
#define H 128
#define IC 16     // valid-i rows per block (pair kernel)
#define JT 64     // valid-j cols per block (4 waves x 16)

typedef __attribute__((ext_vector_type(8))) _Float16 f16x8;
typedef __attribute__((ext_vector_type(4))) float f32x4;

union F8 { uint4 u; f16x8 f; };

// W2-row permutation for the reduce-MFMA epilogue:
// pi(g,m) = (g>=2)*32 + (m>>2)*8 + (g&1)*4 + (m&3)
__device__ __host__ inline int w2perm(int g, int m) {
    return ((g >> 1) << 5) + ((m >> 2) << 3) + ((g & 1) << 2) + (m & 3);
}

// ---------------- kernel 0: build Wpq (f16), permuted W2h/b2p, w3h, b1e ----------------
__global__ void build_w_kernel(const float* __restrict__ W1,
                               const float* __restrict__ W2,
                               const float* __restrict__ b1,
                               const float* __restrict__ b2,
                               const float* __restrict__ W3,
                               _Float16* __restrict__ Wpq,
                               _Float16* __restrict__ W2h,
                               float* __restrict__ b1e,
                               float* __restrict__ b2p,
                               _Float16* __restrict__ w3h) {
    int t = blockIdx.x * blockDim.x + threadIdx.x;   // 0 .. 16383
    if (t < H * D) {
        int h = t >> 7, k = t & 127;
        float wa = W1[h * 384 + k];
        float wb = W1[h * 384 + 128 + k];
        float wc = W1[h * 384 + 256 + k];
        Wpq[h * 128 + k]         = (_Float16)(wa + wc);
        Wpq[(128 + h) * 128 + k] = (_Float16)(wb - wc);
    }
    if (t < 64 * H) {   // permuted W2 rows
        int on = t >> 7, k = t & 127;
        int pi = w2perm(on >> 4, on & 15);
        W2h[t] = (_Float16)W2[pi * 128 + k];
    }
    if (t < 256) b1e[t] = (t < 128) ? b1[t] : 0.f;
    if (t < 64) {
        int pi = w2perm(t >> 4, t & 15);
        b2p[t] = b2[pi];
        w3h[t] = (_Float16)W3[t];
    }
}

// ---------------- kernel 1: per-batch compaction of valid indices ----------------
__global__ __launch_bounds__(64) void scan_kernel(const int* __restrict__ mask,
                                                  int* __restrict__ idx,
                                                  int* __restrict__ cnt) {
    int b = blockIdx.x;
    int lane = threadIdx.x;
    const int* m = mask + b * N;
    int base = 0;
    for (int ch = 0; ch < N / 64; ++ch) {
        int v = m[ch * 64 + lane];
        unsigned long long bal = __ballot(v != 0);
        int pos = base + __popcll(bal & ((1ull << lane) - 1ull));
        if (v) idx[b * N + pos] = ch * 64 + lane;
        base += __popcll(bal);
    }
    if (lane == 0) cnt[b] = base;
}

// ---------------- kernel 2: PQ = f16( F0 @ Wpq^T + b1e ) via f16 MFMA ----------------
__global__ __launch_bounds__(64) void pq_mfma_kernel(const float* __restrict__ F0,
                                                     const _Float16* __restrict__ Wpq,
                                                     const float* __restrict__ b1e,
                                                     _Float16* __restrict__ PQ) {
    int r0 = blockIdx.x * 16;        // F0 row base
    int cb = blockIdx.y * 64;        // output col base
    int lane = threadIdx.x;
    int lp = lane & 15, lg = lane >> 4;

    f16x8 af[4];
    const float* fr = F0 + (size_t)(r0 + lp) * D;
#pragma unroll
    for (int ks = 0; ks < 4; ++ks) {
        float4 a0 = *(const float4*)(fr + ks * 32 + lg * 8);
        float4 a1 = *(const float4*)(fr + ks * 32 + lg * 8 + 4);
        f16x8 v;
        v[0] = (_Float16)a0.x; v[1] = (_Float16)a0.y;
        v[2] = (_Float16)a0.z; v[3] = (_Float16)a0.w;
        v[4] = (_Float16)a1.x; v[5] = (_Float16)a1.y;
        v[6] = (_Float16)a1.z; v[7] = (_Float16)a1.w;
        af[ks] = v;
    }

#pragma unroll
    for (int ct = 0; ct < 4; ++ct) {
        int col = cb + ct * 16 + lp;
        const _Float16* wrow = Wpq + (size_t)col * 128;
        f32x4 acc = 0.f;
#pragma unroll
        for (int ks = 0; ks < 4; ++ks) {
            f16x8 bf = *(const f16x8*)(wrow + ks * 32 + lg * 8);
            acc = __builtin_amdgcn_mfma_f32_16x16x32_f16(af[ks], bf, acc, 0, 0, 0);
        }
        float b1v = b1e[col];
#pragma unroll
        for (int e = 0; e < 4; ++e) {
            int row = r0 + lg * 4 + e;
            PQ[(size_t)row * 256 + col] = (_Float16)(acc[e] + b1v);
        }
    }
}

// ---------------- kernel 3: fused pair MLP over COMPACTED valid pairs ----------------
__global__ __launch_bounds__(256) void pair_mfma_kernel(
        const _Float16* __restrict__ PQ,
        const _Float16* __restrict__ W2h,
        const float* __restrict__ b2p, const _Float16* __restrict__ w3h,
        const float* __restrict__ b3v,
        const int* __restrict__ idx, const int* __restrict__ cnt,
        float* __restrict__ out) {
    int b  = blockIdx.z;
    int nv = cnt[b];
    int i0 = blockIdx.y * IC;
    int j0 = blockIdx.x * JT;
    if (i0 >= nv || j0 >= nv) return;

    int tid  = threadIdx.x;
    int lane = tid & 63;
    int w    = tid >> 6;          // wave 0..3
    int lg   = lane >> 4;         // k-slice group 0..3
    int lp   = lane & 15;         // pair col / row-within-group

    __shared__ uint4 Pl[IC][16];  // P rows (compacted) as f16
    __shared__ int   iI[IC];      // original row index per compacted i

    {
        int r = tid >> 4, c = tid & 15;           // 16 rows x 16 chunks
        int ir = i0 + r;
        int ivr = idx[b * N + (ir < nv ? ir : nv - 1)];
        if (c == 0) iI[r] = ivr;
        Pl[r][c] = *(const uint4*)(PQ + ((size_t)(b * N) + ivr) * 256 + c * 8);
    }
    __syncthreads();

    // W2 fragments (permuted rows), register-resident
    F8 w2f[4][4];
#pragma unroll
    for (int g = 0; g < 4; ++g)
#pragma unroll
        for (int c = 0; c < 4; ++c)
            w2f[g][c].u = *(const uint4*)(W2h + (size_t)(g * 16 + lp) * 128 + c * 32 + lg * 8);

    // Q fragments: lane's compacted pair jj = j0 + w*16 + lp
    int jj   = j0 + w * 16 + lp;
    bool jok = jj < nv;
    int jidx = idx[b * N + (jok ? jj : nv - 1)];
    F8 qf[4];
    {
        const _Float16* qrow = PQ + ((size_t)(b * N) + jidx) * 256 + 128;
#pragma unroll
        for (int c = 0; c < 4; ++c)
            qf[c].u = *(const uint4*)(qrow + c * 32 + lg * 8);
    }

    // epilogue constants
    f32x4 b2v[4];
#pragma unroll
    for (int g = 0; g < 4; ++g)
        b2v[g] = *(const f32x4*)(b2p + g * 16 + lg * 4);
    f16x8 w3f0 = *(const f16x8*)(w3h + lg * 8);
    f16x8 w3f1 = *(const f16x8*)(w3h + 32 + lg * 8);
    float b3s = b3v[0];
    const f32x4 z4 = 0.f;
    const f16x8 zh = (f16x8)(_Float16)0;

    size_t outbase = ((size_t)(b * N)) * N;   // + iI[ii]*N + jidx at store

#define COMPUTE(ACC, II)                                                       \
    {                                                                          \
        _Pragma("unroll")                                                      \
        for (int g = 0; g < 4; ++g) ACC[g] = 0.f;                              \
        __builtin_amdgcn_s_setprio(1);                                         \
        _Pragma("unroll")                                                      \
        for (int c = 0; c < 4; ++c) {                                          \
            F8 ph; ph.u = Pl[II][c * 4 + lg];                                  \
            f16x8 hv = __builtin_elementwise_max(ph.f + qf[c].f, zh);          \
            _Pragma("unroll")                                                  \
            for (int g = 0; g < 4; ++g)                                        \
                ACC[g] = __builtin_amdgcn_mfma_f32_16x16x32_f16(               \
                    w2f[g][c].f, hv, ACC[g], 0, 0, 0);                         \
        }                                                                      \
        __builtin_amdgcn_s_setprio(0);                                         \
    }

#define EPI(ACC, II)                                                           \
    {                                                                          \
        f32x4 t0 = __builtin_elementwise_max(ACC[0] + b2v[0], z4);             \
        f32x4 t1 = __builtin_elementwise_max(ACC[1] + b2v[1], z4);             \
        f32x4 t2 = __builtin_elementwise_max(ACC[2] + b2v[2], z4);             \
        f32x4 t3 = __builtin_elementwise_max(ACC[3] + b2v[3], z4);             \
        f16x8 h0, h1;                                                          \
        h0[0] = (_Float16)t0[0]; h0[1] = (_Float16)t0[1];                      \
        h0[2] = (_Float16)t0[2]; h0[3] = (_Float16)t0[3];                      \
        h0[4] = (_Float16)t1[0]; h0[5] = (_Float16)t1[1];                      \
        h0[6] = (_Float16)t1[2]; h0[7] = (_Float16)t1[3];                      \
        h1[0] = (_Float16)t2[0]; h1[1] = (_Float16)t2[1];                      \
        h1[2] = (_Float16)t2[2]; h1[3] = (_Float16)t2[3];                      \
        h1[4] = (_Float16)t3[0]; h1[5] = (_Float16)t3[1];                      \
        h1[6] = (_Float16)t3[2]; h1[7] = (_Float16)t3[3];                      \
        f32x4 rac = {b3s, b3s, b3s, b3s};                                      \
        rac = __builtin_amdgcn_mfma_f32_16x16x32_f16(w3f0, h0, rac, 0, 0, 0);  \
        rac = __builtin_amdgcn_mfma_f32_16x16x32_f16(w3f1, h1, rac, 0, 0, 0);  \
        float val = 1.f / (1.f + __expf(-rac[0]));                             \
        if (lane < 16 && jok && (i0 + (II)) < nv)                              \
            out[outbase + (size_t)iI[II] * N + jidx] = val;                    \
    }

    f32x4 accA[4], accB[4];
#pragma unroll 1
    for (int ii = 0; ii < IC; ii += 2) {
        COMPUTE(accA, ii)
        COMPUTE(accB, ii + 1)
        EPI(accA, ii)
        EPI(accB, ii + 1)
    }

#undef COMPUTE
#undef EPI
}

extern "C" void kernel_launch(void* const* d_in, const int* in_sizes, int n_in,
                              void* d_out, int out_size, void* d_ws, size_t ws_size,
                              hipStream_t stream) {
    const float* F0  = (const float*)d_in[0];
    const int*   msk = (const int*)  d_in[1];
    const float* W1  = (const float*)d_in[2];
    const float* b1  = (const float*)d_in[3];
    const float* W2  = (const float*)d_in[4];
    const float* b2  = (const float*)d_in[5];
    const float* W3  = (const float*)d_in[6];
    const float* b3  = (const float*)d_in[7];
    float* out = (float*)d_out;

    char* ws = (char*)d_ws;
    _Float16* PQ  = (_Float16*)ws;                                   // 2 MB
    _Float16* Wpq = (_Float16*)(ws + (2u << 20));                    // 64 KB
    _Float16* W2h = (_Float16*)(ws + (2u << 20) + (64u << 10));      // 16 KB
    float*    b1e = (float*)   (ws + (2u << 20) + (80u << 10));      // 1 KB
    float*    b2p = (float*)   (ws + (2u << 20) + (81u << 10));      // 256 B
    _Float16* w3h = (_Float16*)(ws + (2u << 20) + (82u << 10));      // 128 B
    int*      idx = (int*)     (ws + (2u << 20) + (84u << 10));      // 16 KB
    int*      cnt = (int*)     (ws + (2u << 20) + (100u << 10));     // 32 B

    // masked pairs output sigmoid(-1e9) == 0.0f exactly -> zero-fill whole output
    hipMemsetAsync(out, 0, (size_t)B * N * N * sizeof(float), stream);

    build_w_kernel<<<64, 256, 0, stream>>>(W1, W2, b1, b2, W3, Wpq, W2h, b1e, b2p, w3h);
    scan_kernel<<<B, 64, 0, stream>>>(msk, idx, cnt);
    pq_mfma_kernel<<<dim3(B * N / 16, 4), 64, 0, stream>>>(F0, Wpq, b1e, PQ);
    pair_mfma_kernel<<<dim3(N / JT, N / IC, B), 256, 0, stream>>>(
        PQ, W2h, b2p, w3h, b3, idx, cnt, out);
}

// Round 12
// 51.809 us; speedup vs baseline: 2.7543x; 1.0110x over previous
//
#include <hip/hip_runtime.h>

#define B 8
#define N 512
#define D 128
#define H 128
#define IC 16     // valid-i rows per block (pair kernel)
#define JT 64     // valid-j cols per block (4 waves x 16)

typedef __attribute__((ext_vector_type(8))) _Float16 f16x8;
typedef __attribute__((ext_vector_type(4))) float f32x4;

union F8 { uint4 u; f16x8 f; };

// W2-row permutation for the reduce-MFMA epilogue:
// pi(g,m) = (g>=2)*32 + (m>>2)*8 + (g&1)*4 + (m&3)
__device__ __host__ inline int w2perm(int g, int m) {
    return ((g >> 1) << 5) + ((m >> 2) << 3) + ((g & 1) << 2) + (m & 3);
}

// ---------------- kernel F: fast zero-fill of the output ----------------
__global__ __launch_bounds__(256) void fill0_kernel(float4* __restrict__ out, int n4) {
    int i = blockIdx.x * blockDim.x + threadIdx.x;
    if (i < n4) out[i] = float4{0.f, 0.f, 0.f, 0.f};
}

// ---------------- kernel 0: build Wpq (f16), permuted W2h/b2p, w3h, b1e ----------------
__global__ void build_w_kernel(const float* __restrict__ W1,
                               const float* __restrict__ W2,
                               const float* __restrict__ b1,
                               const float* __restrict__ b2,
                               const float* __restrict__ W3,
                               _Float16* __restrict__ Wpq,
                               _Float16* __restrict__ W2h,
                               float* __restrict__ b1e,
                               float* __restrict__ b2p,
                               _Float16* __restrict__ w3h) {
    int t = blockIdx.x * blockDim.x + threadIdx.x;   // 0 .. 16383
    if (t < H * D) {
        int h = t >> 7, k = t & 127;
        float wa = W1[h * 384 + k];
        float wb = W1[h * 384 + 128 + k];
        float wc = W1[h * 384 + 256 + k];
        Wpq[h * 128 + k]         = (_Float16)(wa + wc);
        Wpq[(128 + h) * 128 + k] = (_Float16)(wb - wc);
    }
    if (t < 64 * H) {   // permuted W2 rows
        int on = t >> 7, k = t & 127;
        int pi = w2perm(on >> 4, on & 15);
        W2h[t] = (_Float16)W2[pi * 128 + k];
    }
    if (t < 256) b1e[t] = (t < 128) ? b1[t] : 0.f;
    if (t < 64) {
        int pi = w2perm(t >> 4, t & 15);
        b2p[t] = b2[pi];
        w3h[t] = (_Float16)W3[t];
    }
}

// ---------------- kernel 1: per-batch compaction of valid indices ----------------
__global__ __launch_bounds__(64) void scan_kernel(const int* __restrict__ mask,
                                                  int* __restrict__ idx,
                                                  int* __restrict__ cnt) {
    int b = blockIdx.x;
    int lane = threadIdx.x;
    const int* m = mask + b * N;
    int base = 0;
    for (int ch = 0; ch < N / 64; ++ch) {
        int v = m[ch * 64 + lane];
        unsigned long long bal = __ballot(v != 0);
        int pos = base + __popcll(bal & ((1ull << lane) - 1ull));
        if (v) idx[b * N + pos] = ch * 64 + lane;
        base += __popcll(bal);
    }
    if (lane == 0) cnt[b] = base;
}

// ---------------- kernel 2: PQ = f16( F0 @ Wpq^T + b1e ) via f16 MFMA ----------------
__global__ __launch_bounds__(64) void pq_mfma_kernel(const float* __restrict__ F0,
                                                     const _Float16* __restrict__ Wpq,
                                                     const float* __restrict__ b1e,
                                                     _Float16* __restrict__ PQ) {
    int r0 = blockIdx.x * 16;        // F0 row base
    int cb = blockIdx.y * 64;        // output col base
    int lane = threadIdx.x;
    int lp = lane & 15, lg = lane >> 4;

    f16x8 af[4];
    const float* fr = F0 + (size_t)(r0 + lp) * D;
#pragma unroll
    for (int ks = 0; ks < 4; ++ks) {
        float4 a0 = *(const float4*)(fr + ks * 32 + lg * 8);
        float4 a1 = *(const float4*)(fr + ks * 32 + lg * 8 + 4);
        f16x8 v;
        v[0] = (_Float16)a0.x; v[1] = (_Float16)a0.y;
        v[2] = (_Float16)a0.z; v[3] = (_Float16)a0.w;
        v[4] = (_Float16)a1.x; v[5] = (_Float16)a1.y;
        v[6] = (_Float16)a1.z; v[7] = (_Float16)a1.w;
        af[ks] = v;
    }

#pragma unroll
    for (int ct = 0; ct < 4; ++ct) {
        int col = cb + ct * 16 + lp;
        const _Float16* wrow = Wpq + (size_t)col * 128;
        f32x4 acc = 0.f;
#pragma unroll
        for (int ks = 0; ks < 4; ++ks) {
            f16x8 bf = *(const f16x8*)(wrow + ks * 32 + lg * 8);
            acc = __builtin_amdgcn_mfma_f32_16x16x32_f16(af[ks], bf, acc, 0, 0, 0);
        }
        float b1v = b1e[col];
#pragma unroll
        for (int e = 0; e < 4; ++e) {
            int row = r0 + lg * 4 + e;
            PQ[(size_t)row * 256 + col] = (_Float16)(acc[e] + b1v);
        }
    }
}

// ---------------- kernel 3: fused pair MLP over COMPACTED valid pairs ----------------
__global__ __launch_bounds__(256) void pair_mfma_kernel(
        const _Float16* __restrict__ PQ,
        const _Float16* __restrict__ W2h,
        const float* __restrict__ b2p, const _Float16* __restrict__ w3h,
        const float* __restrict__ b3v,
        const int* __restrict__ idx, const int* __restrict__ cnt,
        float* __restrict__ out) {
    int b  = blockIdx.z;
    int nv = cnt[b];
    int i0 = blockIdx.y * IC;
    int j0 = blockIdx.x * JT;
    if (i0 >= nv || j0 >= nv) return;

    int tid  = threadIdx.x;
    int lane = tid & 63;
    int w    = tid >> 6;          // wave 0..3
    int lg   = lane >> 4;         // k-slice group 0..3
    int lp   = lane & 15;         // pair col / row-within-group

    __shared__ uint4 Pl[IC][16];  // P rows (compacted) as f16
    __shared__ int   iI[IC];      // original row index per compacted i

    {
        int r = tid >> 4, c = tid & 15;           // 16 rows x 16 chunks
        int ir = i0 + r;
        int ivr = idx[b * N + (ir < nv ? ir : nv - 1)];
        if (c == 0) iI[r] = ivr;
        Pl[r][c] = *(const uint4*)(PQ + ((size_t)(b * N) + ivr) * 256 + c * 8);
    }
    __syncthreads();

    // W2 fragments (permuted rows), register-resident
    F8 w2f[4][4];
#pragma unroll
    for (int g = 0; g < 4; ++g)
#pragma unroll
        for (int c = 0; c < 4; ++c)
            w2f[g][c].u = *(const uint4*)(W2h + (size_t)(g * 16 + lp) * 128 + c * 32 + lg * 8);

    // Q fragments: lane's compacted pair jj = j0 + w*16 + lp
    int jj   = j0 + w * 16 + lp;
    bool jok = jj < nv;
    int jidx = idx[b * N + (jok ? jj : nv - 1)];
    F8 qf[4];
    {
        const _Float16* qrow = PQ + ((size_t)(b * N) + jidx) * 256 + 128;
#pragma unroll
        for (int c = 0; c < 4; ++c)
            qf[c].u = *(const uint4*)(qrow + c * 32 + lg * 8);
    }

    // epilogue constants
    f32x4 b2v[4];
#pragma unroll
    for (int g = 0; g < 4; ++g)
        b2v[g] = *(const f32x4*)(b2p + g * 16 + lg * 4);
    f16x8 w3f0 = *(const f16x8*)(w3h + lg * 8);
    f16x8 w3f1 = *(const f16x8*)(w3h + 32 + lg * 8);
    float b3s = b3v[0];
    const f32x4 z4 = 0.f;
    const f16x8 zh = (f16x8)(_Float16)0;

    size_t outbase = ((size_t)(b * N)) * N;   // + iI[ii]*N + jidx at store

#define COMPUTE(ACC, II)                                                       \
    {                                                                          \
        _Pragma("unroll")                                                      \
        for (int g = 0; g < 4; ++g) ACC[g] = 0.f;                              \
        __builtin_amdgcn_s_setprio(1);                                         \
        _Pragma("unroll")                                                      \
        for (int c = 0; c < 4; ++c) {                                          \
            F8 ph; ph.u = Pl[II][c * 4 + lg];                                  \
            f16x8 hv = __builtin_elementwise_max(ph.f + qf[c].f, zh);          \
            _Pragma("unroll")                                                  \
            for (int g = 0; g < 4; ++g)                                        \
                ACC[g] = __builtin_amdgcn_mfma_f32_16x16x32_f16(               \
                    w2f[g][c].f, hv, ACC[g], 0, 0, 0);                         \
        }                                                                      \
        __builtin_amdgcn_s_setprio(0);                                         \
    }

#define EPI(ACC, II)                                                           \
    {                                                                          \
        f32x4 t0 = __builtin_elementwise_max(ACC[0] + b2v[0], z4);             \
        f32x4 t1 = __builtin_elementwise_max(ACC[1] + b2v[1], z4);             \
        f32x4 t2 = __builtin_elementwise_max(ACC[2] + b2v[2], z4);             \
        f32x4 t3 = __builtin_elementwise_max(ACC[3] + b2v[3], z4);             \
        f16x8 h0, h1;                                                          \
        h0[0] = (_Float16)t0[0]; h0[1] = (_Float16)t0[1];                      \
        h0[2] = (_Float16)t0[2]; h0[3] = (_Float16)t0[3];                      \
        h0[4] = (_Float16)t1[0]; h0[5] = (_Float16)t1[1];                      \
        h0[6] = (_Float16)t1[2]; h0[7] = (_Float16)t1[3];                      \
        h1[0] = (_Float16)t2[0]; h1[1] = (_Float16)t2[1];                      \
        h1[2] = (_Float16)t2[2]; h1[3] = (_Float16)t2[3];                      \
        h1[4] = (_Float16)t3[0]; h1[5] = (_Float16)t3[1];                      \
        h1[6] = (_Float16)t3[2]; h1[7] = (_Float16)t3[3];                      \
        f32x4 rac = {b3s, b3s, b3s, b3s};                                      \
        rac = __builtin_amdgcn_mfma_f32_16x16x32_f16(w3f0, h0, rac, 0, 0, 0);  \
        rac = __builtin_amdgcn_mfma_f32_16x16x32_f16(w3f1, h1, rac, 0, 0, 0);  \
        float val = 1.f / (1.f + __expf(-rac[0]));                             \
        if (lane < 16 && jok && (i0 + (II)) < nv)                              \
            out[outbase + (size_t)iI[II] * N + jidx] = val;                    \
    }

    f32x4 accA[4], accB[4];
#pragma unroll 1
    for (int ii = 0; ii < IC; ii += 2) {
        COMPUTE(accA, ii)
        COMPUTE(accB, ii + 1)
        EPI(accA, ii)
        EPI(accB, ii + 1)
    }

#undef COMPUTE
#undef EPI
}

extern "C" void kernel_launch(void* const* d_in, const int* in_sizes, int n_in,
                              void* d_out, int out_size, void* d_ws, size_t ws_size,
                              hipStream_t stream) {
    const float* F0  = (const float*)d_in[0];
    const int*   msk = (const int*)  d_in[1];
    const float* W1  = (const float*)d_in[2];
    const float* b1  = (const float*)d_in[3];
    const float* W2  = (const float*)d_in[4];
    const float* b2  = (const float*)d_in[5];
    const float* W3  = (const float*)d_in[6];
    const float* b3  = (const float*)d_in[7];
    float* out = (float*)d_out;

    char* ws = (char*)d_ws;
    _Float16* PQ  = (_Float16*)ws;                                   // 2 MB
    _Float16* Wpq = (_Float16*)(ws + (2u << 20));                    // 64 KB
    _Float16* W2h = (_Float16*)(ws + (2u << 20) + (64u << 10));      // 16 KB
    float*    b1e = (float*)   (ws + (2u << 20) + (80u << 10));      // 1 KB
    float*    b2p = (float*)   (ws + (2u << 20) + (81u << 10));      // 256 B
    _Float16* w3h = (_Float16*)(ws + (2u << 20) + (82u << 10));      // 128 B
    int*      idx = (int*)     (ws + (2u << 20) + (84u << 10));      // 16 KB
    int*      cnt = (int*)     (ws + (2u << 20) + (100u << 10));     // 32 B

    // masked pairs output sigmoid(-1e9) == 0.0f exactly -> zero-fill output
    // (custom kernel: rocclr fillBuffer ran at 207 GB/s / 40 us for 8.4 MB)
    int n4 = (B * N * N) / 4;     // 524288 float4s
    fill0_kernel<<<(n4 + 255) / 256, 256, 0, stream>>>((float4*)out, n4);

    build_w_kernel<<<64, 256, 0, stream>>>(W1, W2, b1, b2, W3, Wpq, W2h, b1e, b2p, w3h);
    scan_kernel<<<B, 64, 0, stream>>>(msk, idx, cnt);
    pq_mfma_kernel<<<dim3(B * N / 16, 4), 64, 0, stream>>>(F0, Wpq, b1e, PQ);
    pair_mfma_kernel<<<dim3(N / JT, N / IC, B), 256, 0, stream>>>(
        PQ, W2h, b2p, w3h, b3, idx, cnt, out);
}

// Round 13
// 48.559 us; speedup vs baseline: 2.9387x; 1.0669x over previous
//
#include <hip/hip_runtime.h>

#define B 8
#define N 512
#define D 128
#define H 128
#define IC 16     // valid-i rows per block (pair kernel)
#define JT 64     // valid-j cols per block (4 waves x 16)

typedef __attribute__((ext_vector_type(8))) _Float16 f16x8;
typedef __attribute__((ext_vector_type(4))) float f32x4;

union F8 { uint4 u; f16x8 f; };

// W2-row permutation for the reduce-MFMA epilogue:
// pi(g,m) = (g>=2)*32 + (m>>2)*8 + (g&1)*4 + (m&3)
__device__ __host__ inline int w2perm(int g, int m) {
    return ((g >> 1) << 5) + ((m >> 2) << 3) + ((g & 1) << 2) + (m & 3);
}

// ---------------- kernel F: fast zero-fill of the output ----------------
__global__ __launch_bounds__(256) void fill0_kernel(float4* __restrict__ out, int n4) {
    int i = blockIdx.x * blockDim.x + threadIdx.x;
    if (i < n4) out[i] = float4{0.f, 0.f, 0.f, 0.f};
}

// ---------------- kernel 0: build Wpq (f16), permuted W2h/b2p, w3h, b1e ----------------
__global__ void build_w_kernel(const float* __restrict__ W1,
                               const float* __restrict__ W2,
                               const float* __restrict__ b1,
                               const float* __restrict__ b2,
                               const float* __restrict__ W3,
                               _Float16* __restrict__ Wpq,
                               _Float16* __restrict__ W2h,
                               float* __restrict__ b1e,
                               float* __restrict__ b2p,
                               _Float16* __restrict__ w3h) {
    int t = blockIdx.x * blockDim.x + threadIdx.x;   // 0 .. 16383
    if (t < H * D) {
        int h = t >> 7, k = t & 127;
        float wa = W1[h * 384 + k];
        float wb = W1[h * 384 + 128 + k];
        float wc = W1[h * 384 + 256 + k];
        Wpq[h * 128 + k]         = (_Float16)(wa + wc);
        Wpq[(128 + h) * 128 + k] = (_Float16)(wb - wc);
    }
    if (t < 64 * H) {   // permuted W2 rows
        int on = t >> 7, k = t & 127;
        int pi = w2perm(on >> 4, on & 15);
        W2h[t] = (_Float16)W2[pi * 128 + k];
    }
    if (t < 256) b1e[t] = (t < 128) ? b1[t] : 0.f;
    if (t < 64) {
        int pi = w2perm(t >> 4, t & 15);
        b2p[t] = b2[pi];
        w3h[t] = (_Float16)W3[t];
    }
}

// ---------------- kernel 1: compaction + tile-count prefix (single block) ----------------
__global__ __launch_bounds__(64) void scan_kernel(const int* __restrict__ mask,
                                                  int* __restrict__ idx,
                                                  int* __restrict__ cnt,
                                                  int* __restrict__ tpre) {
    int lane = threadIdx.x;
    int pre = 0;
    for (int b = 0; b < B; ++b) {
        const int* m = mask + b * N;
        int base = 0;
        for (int ch = 0; ch < N / 64; ++ch) {
            int v = m[ch * 64 + lane];
            unsigned long long bal = __ballot(v != 0);
            int pos = base + __popcll(bal & ((1ull << lane) - 1ull));
            if (v) idx[b * N + pos] = ch * 64 + lane;
            base += __popcll(bal);
        }
        if (lane == 0) { cnt[b] = base; tpre[b] = pre; }
        int nTi = (base + IC - 1) / IC;
        int nTj = (base + JT - 1) / JT;
        pre += nTi * nTj;
    }
    if (lane == 0) tpre[B] = pre;
}

// ---------------- kernel 2: PQ = f16( F0 @ Wpq^T + b1e ) via f16 MFMA ----------------
__global__ __launch_bounds__(64) void pq_mfma_kernel(const float* __restrict__ F0,
                                                     const _Float16* __restrict__ Wpq,
                                                     const float* __restrict__ b1e,
                                                     _Float16* __restrict__ PQ) {
    int r0 = blockIdx.x * 16;        // F0 row base
    int cb = blockIdx.y * 64;        // output col base
    int lane = threadIdx.x;
    int lp = lane & 15, lg = lane >> 4;

    f16x8 af[4];
    const float* fr = F0 + (size_t)(r0 + lp) * D;
#pragma unroll
    for (int ks = 0; ks < 4; ++ks) {
        float4 a0 = *(const float4*)(fr + ks * 32 + lg * 8);
        float4 a1 = *(const float4*)(fr + ks * 32 + lg * 8 + 4);
        f16x8 v;
        v[0] = (_Float16)a0.x; v[1] = (_Float16)a0.y;
        v[2] = (_Float16)a0.z; v[3] = (_Float16)a0.w;
        v[4] = (_Float16)a1.x; v[5] = (_Float16)a1.y;
        v[6] = (_Float16)a1.z; v[7] = (_Float16)a1.w;
        af[ks] = v;
    }

#pragma unroll
    for (int ct = 0; ct < 4; ++ct) {
        int col = cb + ct * 16 + lp;
        const _Float16* wrow = Wpq + (size_t)col * 128;
        f32x4 acc = 0.f;
#pragma unroll
        for (int ks = 0; ks < 4; ++ks) {
            f16x8 bf = *(const f16x8*)(wrow + ks * 32 + lg * 8);
            acc = __builtin_amdgcn_mfma_f32_16x16x32_f16(af[ks], bf, acc, 0, 0, 0);
        }
        float b1v = b1e[col];
#pragma unroll
        for (int e = 0; e < 4; ++e) {
            int row = r0 + lg * 4 + e;
            PQ[(size_t)row * 256 + col] = (_Float16)(acc[e] + b1v);
        }
    }
}

// ---------------- kernel 3: fused pair MLP, flat grid over valid tiles ----------------
__global__ __launch_bounds__(256) void pair_mfma_kernel(
        const _Float16* __restrict__ PQ,
        const _Float16* __restrict__ W2h,
        const float* __restrict__ b2p, const _Float16* __restrict__ w3h,
        const float* __restrict__ b3v,
        const int* __restrict__ idx, const int* __restrict__ cnt,
        const int* __restrict__ tpre,
        float* __restrict__ out) {
    int t = blockIdx.x;
    if (t >= tpre[B]) return;              // contiguous dead tail
    int b = 0;
#pragma unroll
    for (int k = 1; k < B; ++k) b += (t >= tpre[k]) ? 1 : 0;
    int nv    = cnt[b];
    int local = t - tpre[b];
    int nTj   = (nv + JT - 1) / JT;
    int i0    = (local / nTj) * IC;
    int j0    = (local % nTj) * JT;

    int tid  = threadIdx.x;
    int lane = tid & 63;
    int w    = tid >> 6;          // wave 0..3
    int lg   = lane >> 4;         // k-slice group 0..3
    int lp   = lane & 15;         // pair col / row-within-group

    __shared__ uint4 Pl[IC][16];  // P rows (compacted) as f16
    __shared__ int   iI[IC];      // original row index per compacted i

    {
        int r = tid >> 4, c = tid & 15;           // 16 rows x 16 chunks
        int ir = i0 + r;
        int ivr = idx[b * N + (ir < nv ? ir : nv - 1)];
        if (c == 0) iI[r] = ivr;
        Pl[r][c] = *(const uint4*)(PQ + ((size_t)(b * N) + ivr) * 256 + c * 8);
    }
    __syncthreads();

    // W2 fragments (permuted rows), register-resident
    F8 w2f[4][4];
#pragma unroll
    for (int g = 0; g < 4; ++g)
#pragma unroll
        for (int c = 0; c < 4; ++c)
            w2f[g][c].u = *(const uint4*)(W2h + (size_t)(g * 16 + lp) * 128 + c * 32 + lg * 8);

    // Q fragments: lane's compacted pair jj = j0 + w*16 + lp
    int jj   = j0 + w * 16 + lp;
    bool jok = jj < nv;
    int jidx = idx[b * N + (jok ? jj : nv - 1)];
    F8 qf[4];
    {
        const _Float16* qrow = PQ + ((size_t)(b * N) + jidx) * 256 + 128;
#pragma unroll
        for (int c = 0; c < 4; ++c)
            qf[c].u = *(const uint4*)(qrow + c * 32 + lg * 8);
    }

    // epilogue constants
    f32x4 b2v[4];
#pragma unroll
    for (int g = 0; g < 4; ++g)
        b2v[g] = *(const f32x4*)(b2p + g * 16 + lg * 4);
    f16x8 w3f0 = *(const f16x8*)(w3h + lg * 8);
    f16x8 w3f1 = *(const f16x8*)(w3h + 32 + lg * 8);
    float b3s = b3v[0];
    const f32x4 z4 = 0.f;
    const f16x8 zh = (f16x8)(_Float16)0;

    size_t outbase = ((size_t)(b * N)) * N;   // + iI[ii]*N + jidx at store

#define COMPUTE(ACC, II)                                                       \
    {                                                                          \
        _Pragma("unroll")                                                      \
        for (int g = 0; g < 4; ++g) ACC[g] = 0.f;                              \
        __builtin_amdgcn_s_setprio(1);                                         \
        _Pragma("unroll")                                                      \
        for (int c = 0; c < 4; ++c) {                                          \
            F8 ph; ph.u = Pl[II][c * 4 + lg];                                  \
            f16x8 hv = __builtin_elementwise_max(ph.f + qf[c].f, zh);          \
            _Pragma("unroll")                                                  \
            for (int g = 0; g < 4; ++g)                                        \
                ACC[g] = __builtin_amdgcn_mfma_f32_16x16x32_f16(               \
                    w2f[g][c].f, hv, ACC[g], 0, 0, 0);                         \
        }                                                                      \
        __builtin_amdgcn_s_setprio(0);                                         \
    }

#define EPI(ACC, II)                                                           \
    {                                                                          \
        f32x4 t0 = __builtin_elementwise_max(ACC[0] + b2v[0], z4);             \
        f32x4 t1 = __builtin_elementwise_max(ACC[1] + b2v[1], z4);             \
        f32x4 t2 = __builtin_elementwise_max(ACC[2] + b2v[2], z4);             \
        f32x4 t3 = __builtin_elementwise_max(ACC[3] + b2v[3], z4);             \
        f16x8 h0, h1;                                                          \
        h0[0] = (_Float16)t0[0]; h0[1] = (_Float16)t0[1];                      \
        h0[2] = (_Float16)t0[2]; h0[3] = (_Float16)t0[3];                      \
        h0[4] = (_Float16)t1[0]; h0[5] = (_Float16)t1[1];                      \
        h0[6] = (_Float16)t1[2]; h0[7] = (_Float16)t1[3];                      \
        h1[0] = (_Float16)t2[0]; h1[1] = (_Float16)t2[1];                      \
        h1[2] = (_Float16)t2[2]; h1[3] = (_Float16)t2[3];                      \
        h1[4] = (_Float16)t3[0]; h1[5] = (_Float16)t3[1];                      \
        h1[6] = (_Float16)t3[2]; h1[7] = (_Float16)t3[3];                      \
        f32x4 rac = {b3s, b3s, b3s, b3s};                                      \
        rac = __builtin_amdgcn_mfma_f32_16x16x32_f16(w3f0, h0, rac, 0, 0, 0);  \
        rac = __builtin_amdgcn_mfma_f32_16x16x32_f16(w3f1, h1, rac, 0, 0, 0);  \
        float val = 1.f / (1.f + __expf(-rac[0]));                             \
        if (lane < 16 && jok && (i0 + (II)) < nv)                              \
            out[outbase + (size_t)iI[II] * N + jidx] = val;                    \
    }

    f32x4 accA[4], accB[4];
#pragma unroll 1
    for (int ii = 0; ii < IC; ii += 2) {
        COMPUTE(accA, ii)
        COMPUTE(accB, ii + 1)
        EPI(accA, ii)
        EPI(accB, ii + 1)
    }

#undef COMPUTE
#undef EPI
}

extern "C" void kernel_launch(void* const* d_in, const int* in_sizes, int n_in,
                              void* d_out, int out_size, void* d_ws, size_t ws_size,
                              hipStream_t stream) {
    const float* F0  = (const float*)d_in[0];
    const int*   msk = (const int*)  d_in[1];
    const float* W1  = (const float*)d_in[2];
    const float* b1  = (const float*)d_in[3];
    const float* W2  = (const float*)d_in[4];
    const float* b2  = (const float*)d_in[5];
    const float* W3  = (const float*)d_in[6];
    const float* b3  = (const float*)d_in[7];
    float* out = (float*)d_out;

    char* ws = (char*)d_ws;
    _Float16* PQ  = (_Float16*)ws;                                   // 2 MB
    _Float16* Wpq = (_Float16*)(ws + (2u << 20));                    // 64 KB
    _Float16* W2h = (_Float16*)(ws + (2u << 20) + (64u << 10));      // 16 KB
    float*    b1e = (float*)   (ws + (2u << 20) + (80u << 10));      // 1 KB
    float*    b2p = (float*)   (ws + (2u << 20) + (81u << 10));      // 256 B
    _Float16* w3h = (_Float16*)(ws + (2u << 20) + (82u << 10));      // 128 B
    int*      idx = (int*)     (ws + (2u << 20) + (84u << 10));      // 16 KB
    int*      cnt = (int*)     (ws + (2u << 20) + (100u << 10));     // 64 B
    int*      tpre= (int*)     (ws + (2u << 20) + (100u << 10) + 64);// 64 B

    // masked pairs output sigmoid(-1e9) == 0.0f exactly -> zero-fill output
    int n4 = (B * N * N) / 4;     // 524288 float4s
    fill0_kernel<<<(n4 + 255) / 256, 256, 0, stream>>>((float4*)out, n4);

    build_w_kernel<<<64, 256, 0, stream>>>(W1, W2, b1, b2, W3, Wpq, W2h, b1e, b2p, w3h);
    scan_kernel<<<1, 64, 0, stream>>>(msk, idx, cnt, tpre);
    pq_mfma_kernel<<<dim3(B * N / 16, 4), 64, 0, stream>>>(F0, Wpq, b1e, PQ);

    int maxTiles = B * ((N + IC - 1) / IC) * ((N + JT - 1) / JT);    // 2048
    pair_mfma_kernel<<<maxTiles, 256, 0, stream>>>(
        PQ, W2h, b2p, w3h, b3, idx, cnt, tpre, out);
}

// Round 14
// 43.295 us; speedup vs baseline: 3.2960x; 1.1216x over previous
//
#include <hip/hip_runtime.h>

#define B 8
#define N 512
#define D 128
#define H 128
#define IC 8      // valid-i rows per block (pair kernel)
#define JT 64     // valid-j cols per block (4 waves x 16)

typedef __attribute__((ext_vector_type(8))) _Float16 f16x8;
typedef __attribute__((ext_vector_type(4))) float f32x4;

union F8 { uint4 u; f16x8 f; };

// W2-row permutation for the reduce-MFMA epilogue:
// pi(g,m) = (g>=2)*32 + (m>>2)*8 + (g&1)*4 + (m&3)
__device__ __host__ inline int w2perm(int g, int m) {
    return ((g >> 1) << 5) + ((m >> 2) << 3) + ((g & 1) << 2) + (m & 3);
}

// ---------------- kernel F: fast zero-fill of the output ----------------
__global__ __launch_bounds__(256) void fill0_kernel(float4* __restrict__ out, int n4) {
    int i = blockIdx.x * blockDim.x + threadIdx.x;
    if (i < n4) out[i] = float4{0.f, 0.f, 0.f, 0.f};
}

// ---------------- kernel 0: build Wpq (f16), permuted W2h/b2p, w3h, b1e ----------------
__global__ void build_w_kernel(const float* __restrict__ W1,
                               const float* __restrict__ W2,
                               const float* __restrict__ b1,
                               const float* __restrict__ b2,
                               const float* __restrict__ W3,
                               _Float16* __restrict__ Wpq,
                               _Float16* __restrict__ W2h,
                               float* __restrict__ b1e,
                               float* __restrict__ b2p,
                               _Float16* __restrict__ w3h) {
    int t = blockIdx.x * blockDim.x + threadIdx.x;   // 0 .. 16383
    if (t < H * D) {
        int h = t >> 7, k = t & 127;
        float wa = W1[h * 384 + k];
        float wb = W1[h * 384 + 128 + k];
        float wc = W1[h * 384 + 256 + k];
        Wpq[h * 128 + k]         = (_Float16)(wa + wc);
        Wpq[(128 + h) * 128 + k] = (_Float16)(wb - wc);
    }
    if (t < 64 * H) {   // permuted W2 rows
        int on = t >> 7, k = t & 127;
        int pi = w2perm(on >> 4, on & 15);
        W2h[t] = (_Float16)W2[pi * 128 + k];
    }
    if (t < 256) b1e[t] = (t < 128) ? b1[t] : 0.f;
    if (t < 64) {
        int pi = w2perm(t >> 4, t & 15);
        b2p[t] = b2[pi];
        w3h[t] = (_Float16)W3[t];
    }
}

// ---------------- kernel 1: per-batch compaction (8 parallel blocks) ----------------
__global__ __launch_bounds__(64) void scan_kernel(const int* __restrict__ mask,
                                                  int* __restrict__ idx,
                                                  int* __restrict__ cnt) {
    int b = blockIdx.x;
    int lane = threadIdx.x;
    const int* m = mask + b * N;
    int base = 0;
    for (int ch = 0; ch < N / 64; ++ch) {
        int v = m[ch * 64 + lane];
        unsigned long long bal = __ballot(v != 0);
        int pos = base + __popcll(bal & ((1ull << lane) - 1ull));
        if (v) idx[b * N + pos] = ch * 64 + lane;
        base += __popcll(bal);
    }
    if (lane == 0) cnt[b] = base;
}

// ---------------- kernel 2: PQ = f16( F0 @ Wpq^T + b1e ), coalesced stores ----------------
__global__ __launch_bounds__(64) void pq_mfma_kernel(const float* __restrict__ F0,
                                                     const _Float16* __restrict__ Wpq,
                                                     const float* __restrict__ b1e,
                                                     _Float16* __restrict__ PQ) {
    int r0 = blockIdx.x * 16;        // F0 row base
    int cb = blockIdx.y * 64;        // output col base
    int lane = threadIdx.x;
    int lp = lane & 15, lg = lane >> 4;

    __shared__ _Float16 T[16][64];   // 2 KB transpose staging

    f16x8 af[4];
    const float* fr = F0 + (size_t)(r0 + lp) * D;
#pragma unroll
    for (int ks = 0; ks < 4; ++ks) {
        float4 a0 = *(const float4*)(fr + ks * 32 + lg * 8);
        float4 a1 = *(const float4*)(fr + ks * 32 + lg * 8 + 4);
        f16x8 v;
        v[0] = (_Float16)a0.x; v[1] = (_Float16)a0.y;
        v[2] = (_Float16)a0.z; v[3] = (_Float16)a0.w;
        v[4] = (_Float16)a1.x; v[5] = (_Float16)a1.y;
        v[6] = (_Float16)a1.z; v[7] = (_Float16)a1.w;
        af[ks] = v;
    }

#pragma unroll
    for (int ct = 0; ct < 4; ++ct) {
        int col = cb + ct * 16 + lp;
        const _Float16* wrow = Wpq + (size_t)col * 128;
        f32x4 acc = 0.f;
#pragma unroll
        for (int ks = 0; ks < 4; ++ks) {
            f16x8 bf = *(const f16x8*)(wrow + ks * 32 + lg * 8);
            acc = __builtin_amdgcn_mfma_f32_16x16x32_f16(af[ks], bf, acc, 0, 0, 0);
        }
        float b1v = b1e[col];
#pragma unroll
        for (int e = 0; e < 4; ++e)
            T[lg * 4 + e][ct * 16 + lp] = (_Float16)(acc[e] + b1v);
    }
    __syncthreads();

    // coalesced store: 4 lanes per row, 32B each -> 128B/row contiguous
    int r  = lane >> 2;
    int c4 = (lane & 3) * 16;
    uint4 v0 = *(const uint4*)&T[r][c4];
    uint4 v1 = *(const uint4*)&T[r][c4 + 8];
    _Float16* dst = PQ + (size_t)(r0 + r) * 256 + cb + c4;
    *(uint4*)dst       = v0;
    *(uint4*)(dst + 8) = v1;
}

// ---------------- kernel 3: fused pair MLP, flat grid over valid tiles ----------------
__global__ __launch_bounds__(256) void pair_mfma_kernel(
        const _Float16* __restrict__ PQ,
        const _Float16* __restrict__ W2h,
        const float* __restrict__ b2p, const _Float16* __restrict__ w3h,
        const float* __restrict__ b3v,
        const int* __restrict__ idx, const int* __restrict__ cnt,
        float* __restrict__ out) {
    int t = blockIdx.x;
    // map flat tile id -> (b, i0, j0) via per-batch tile counts from cnt[]
    int b = -1, local = 0, nv = 0, acc = 0;
#pragma unroll
    for (int k = 0; k < B; ++k) {
        int c   = cnt[k];
        int nTi = (c + IC - 1) / IC;
        int nTj = (c + JT - 1) / JT;
        int tl  = nTi * nTj;
        if (b < 0 && t < acc + tl) { b = k; local = t - acc; nv = c; }
        acc += tl;
    }
    if (b < 0) return;                 // contiguous dead tail
    int nTj = (nv + JT - 1) / JT;
    int i0  = (local / nTj) * IC;
    int j0  = (local % nTj) * JT;

    int tid  = threadIdx.x;
    int lane = tid & 63;
    int w    = tid >> 6;          // wave 0..3
    int lg   = lane >> 4;         // k-slice group 0..3
    int lp   = lane & 15;         // pair col / row-within-group

    __shared__ uint4 Pl[IC][16];  // P rows (compacted) as f16
    __shared__ int   iI[IC];      // original row index per compacted i

    if (tid < IC * 16) {
        int r = tid >> 4, c = tid & 15;
        int ir = i0 + r;
        int ivr = idx[b * N + (ir < nv ? ir : nv - 1)];
        if (c == 0) iI[r] = ivr;
        Pl[r][c] = *(const uint4*)(PQ + ((size_t)(b * N) + ivr) * 256 + c * 8);
    }
    __syncthreads();

    // W2 fragments (permuted rows), register-resident
    F8 w2f[4][4];
#pragma unroll
    for (int g = 0; g < 4; ++g)
#pragma unroll
        for (int c = 0; c < 4; ++c)
            w2f[g][c].u = *(const uint4*)(W2h + (size_t)(g * 16 + lp) * 128 + c * 32 + lg * 8);

    // Q fragments: lane's compacted pair jj = j0 + w*16 + lp
    int jj   = j0 + w * 16 + lp;
    bool jok = jj < nv;
    int jidx = idx[b * N + (jok ? jj : nv - 1)];
    F8 qf[4];
    {
        const _Float16* qrow = PQ + ((size_t)(b * N) + jidx) * 256 + 128;
#pragma unroll
        for (int c = 0; c < 4; ++c)
            qf[c].u = *(const uint4*)(qrow + c * 32 + lg * 8);
    }

    // epilogue constants
    f32x4 b2v[4];
#pragma unroll
    for (int g = 0; g < 4; ++g)
        b2v[g] = *(const f32x4*)(b2p + g * 16 + lg * 4);
    f16x8 w3f0 = *(const f16x8*)(w3h + lg * 8);
    f16x8 w3f1 = *(const f16x8*)(w3h + 32 + lg * 8);
    float b3s = b3v[0];
    const f32x4 z4 = 0.f;
    const f16x8 zh = (f16x8)(_Float16)0;

    size_t outbase = ((size_t)(b * N)) * N;

#define COMPUTE(ACC, II)                                                       \
    {                                                                          \
        _Pragma("unroll")                                                      \
        for (int g = 0; g < 4; ++g) ACC[g] = 0.f;                              \
        __builtin_amdgcn_s_setprio(1);                                         \
        _Pragma("unroll")                                                      \
        for (int c = 0; c < 4; ++c) {                                          \
            F8 ph; ph.u = Pl[II][c * 4 + lg];                                  \
            f16x8 hv = __builtin_elementwise_max(ph.f + qf[c].f, zh);          \
            _Pragma("unroll")                                                  \
            for (int g = 0; g < 4; ++g)                                        \
                ACC[g] = __builtin_amdgcn_mfma_f32_16x16x32_f16(               \
                    w2f[g][c].f, hv, ACC[g], 0, 0, 0);                         \
        }                                                                      \
        __builtin_amdgcn_s_setprio(0);                                         \
    }

#define EPI(ACC, II)                                                           \
    {                                                                          \
        f32x4 t0 = __builtin_elementwise_max(ACC[0] + b2v[0], z4);             \
        f32x4 t1 = __builtin_elementwise_max(ACC[1] + b2v[1], z4);             \
        f32x4 t2 = __builtin_elementwise_max(ACC[2] + b2v[2], z4);             \
        f32x4 t3 = __builtin_elementwise_max(ACC[3] + b2v[3], z4);             \
        f16x8 h0, h1;                                                          \
        h0[0] = (_Float16)t0[0]; h0[1] = (_Float16)t0[1];                      \
        h0[2] = (_Float16)t0[2]; h0[3] = (_Float16)t0[3];                      \
        h0[4] = (_Float16)t1[0]; h0[5] = (_Float16)t1[1];                      \
        h0[6] = (_Float16)t1[2]; h0[7] = (_Float16)t1[3];                      \
        h1[0] = (_Float16)t2[0]; h1[1] = (_Float16)t2[1];                      \
        h1[2] = (_Float16)t2[2]; h1[3] = (_Float16)t2[3];                      \
        h1[4] = (_Float16)t3[0]; h1[5] = (_Float16)t3[1];                      \
        h1[6] = (_Float16)t3[2]; h1[7] = (_Float16)t3[3];                      \
        f32x4 rac = {b3s, b3s, b3s, b3s};                                      \
        rac = __builtin_amdgcn_mfma_f32_16x16x32_f16(w3f0, h0, rac, 0, 0, 0);  \
        rac = __builtin_amdgcn_mfma_f32_16x16x32_f16(w3f1, h1, rac, 0, 0, 0);  \
        float val = 1.f / (1.f + __expf(-rac[0]));                             \
        if (lane < 16 && jok && (i0 + (II)) < nv)                              \
            out[outbase + (size_t)iI[II] * N + jidx] = val;                    \
    }

    f32x4 accA[4], accB[4];
#pragma unroll 1
    for (int ii = 0; ii < IC; ii += 2) {
        COMPUTE(accA, ii)
        COMPUTE(accB, ii + 1)
        EPI(accA, ii)
        EPI(accB, ii + 1)
    }

#undef COMPUTE
#undef EPI
}

extern "C" void kernel_launch(void* const* d_in, const int* in_sizes, int n_in,
                              void* d_out, int out_size, void* d_ws, size_t ws_size,
                              hipStream_t stream) {
    const float* F0  = (const float*)d_in[0];
    const int*   msk = (const int*)  d_in[1];
    const float* W1  = (const float*)d_in[2];
    const float* b1  = (const float*)d_in[3];
    const float* W2  = (const float*)d_in[4];
    const float* b2  = (const float*)d_in[5];
    const float* W3  = (const float*)d_in[6];
    const float* b3  = (const float*)d_in[7];
    float* out = (float*)d_out;

    char* ws = (char*)d_ws;
    _Float16* PQ  = (_Float16*)ws;                                   // 2 MB
    _Float16* Wpq = (_Float16*)(ws + (2u << 20));                    // 64 KB
    _Float16* W2h = (_Float16*)(ws + (2u << 20) + (64u << 10));      // 16 KB
    float*    b1e = (float*)   (ws + (2u << 20) + (80u << 10));      // 1 KB
    float*    b2p = (float*)   (ws + (2u << 20) + (81u << 10));      // 256 B
    _Float16* w3h = (_Float16*)(ws + (2u << 20) + (82u << 10));      // 128 B
    int*      idx = (int*)     (ws + (2u << 20) + (84u << 10));      // 16 KB
    int*      cnt = (int*)     (ws + (2u << 20) + (100u << 10));     // 64 B

    // masked pairs output sigmoid(-1e9) == 0.0f exactly -> zero-fill output
    int n4 = (B * N * N) / 4;     // 524288 float4s
    fill0_kernel<<<(n4 + 255) / 256, 256, 0, stream>>>((float4*)out, n4);

    build_w_kernel<<<64, 256, 0, stream>>>(W1, W2, b1, b2, W3, Wpq, W2h, b1e, b2p, w3h);
    scan_kernel<<<B, 64, 0, stream>>>(msk, idx, cnt);
    pq_mfma_kernel<<<dim3(B * N / 16, 4), 64, 0, stream>>>(F0, Wpq, b1e, PQ);

    int maxTiles = B * ((N + IC - 1) / IC) * ((N + JT - 1) / JT);    // 4096
    pair_mfma_kernel<<<maxTiles, 256, 0, stream>>>(
        PQ, W2h, b2p, w3h, b3, idx, cnt, out);
}

// Round 15
// 41.844 us; speedup vs baseline: 3.4103x; 1.0347x over previous
//
#include <hip/hip_runtime.h>

#define B 8
#define N 512
#define D 128
#define H 128
#define IC 8      // valid-i rows per block (pair kernel)
#define JT 64     // valid-j cols per block (4 waves x 16)

typedef __attribute__((ext_vector_type(8))) _Float16 f16x8;
typedef __attribute__((ext_vector_type(4))) float f32x4;

union F8 { uint4 u; f16x8 f; };

// W2-row permutation for the reduce-MFMA epilogue:
// pi(g,m) = (g>=2)*32 + (m>>2)*8 + (g&1)*4 + (m&3)
__device__ __host__ inline int w2perm(int g, int m) {
    return ((g >> 1) << 5) + ((m >> 2) << 3) + ((g & 1) << 2) + (m & 3);
}

// ---------------- kernel F: fast zero-fill of the output ----------------
__global__ __launch_bounds__(256) void fill0_kernel(float4* __restrict__ out, int n4) {
    int i = blockIdx.x * blockDim.x + threadIdx.x;
    if (i < n4) out[i] = float4{0.f, 0.f, 0.f, 0.f};
}

// ---------------- kernel 0: build Wpq (f16), permuted W2h/b2p, w3h, b1e ----------------
__global__ void build_w_kernel(const float* __restrict__ W1,
                               const float* __restrict__ W2,
                               const float* __restrict__ b1,
                               const float* __restrict__ b2,
                               const float* __restrict__ W3,
                               _Float16* __restrict__ Wpq,
                               _Float16* __restrict__ W2h,
                               float* __restrict__ b1e,
                               float* __restrict__ b2p,
                               _Float16* __restrict__ w3h) {
    int t = blockIdx.x * blockDim.x + threadIdx.x;   // 0 .. 16383
    if (t < H * D) {
        int h = t >> 7, k = t & 127;
        float wa = W1[h * 384 + k];
        float wb = W1[h * 384 + 128 + k];
        float wc = W1[h * 384 + 256 + k];
        Wpq[h * 128 + k]         = (_Float16)(wa + wc);
        Wpq[(128 + h) * 128 + k] = (_Float16)(wb - wc);
    }
    if (t < 64 * H) {   // permuted W2 rows
        int on = t >> 7, k = t & 127;
        int pi = w2perm(on >> 4, on & 15);
        W2h[t] = (_Float16)W2[pi * 128 + k];
    }
    if (t < 256) b1e[t] = (t < 128) ? b1[t] : 0.f;
    if (t < 64) {
        int pi = w2perm(t >> 4, t & 15);
        b2p[t] = b2[pi];
        w3h[t] = (_Float16)W3[t];
    }
}

// ---------------- kernel 1: per-batch compaction (8 parallel blocks) ----------------
__global__ __launch_bounds__(64) void scan_kernel(const int* __restrict__ mask,
                                                  int* __restrict__ idx,
                                                  int* __restrict__ cnt) {
    int b = blockIdx.x;
    int lane = threadIdx.x;
    const int* m = mask + b * N;
    int base = 0;
    for (int ch = 0; ch < N / 64; ++ch) {
        int v = m[ch * 64 + lane];
        unsigned long long bal = __ballot(v != 0);
        int pos = base + __popcll(bal & ((1ull << lane) - 1ull));
        if (v) idx[b * N + pos] = ch * 64 + lane;
        base += __popcll(bal);
    }
    if (lane == 0) cnt[b] = base;
}

// ---------------- kernel 2: PQ = f16( F0 @ Wpq^T + b1e ), coalesced stores ----------------
__global__ __launch_bounds__(64) void pq_mfma_kernel(const float* __restrict__ F0,
                                                     const _Float16* __restrict__ Wpq,
                                                     const float* __restrict__ b1e,
                                                     _Float16* __restrict__ PQ) {
    int r0 = blockIdx.x * 16;        // F0 row base
    int cb = blockIdx.y * 64;        // output col base
    int lane = threadIdx.x;
    int lp = lane & 15, lg = lane >> 4;

    __shared__ _Float16 T[16][64];   // 2 KB transpose staging

    f16x8 af[4];
    const float* fr = F0 + (size_t)(r0 + lp) * D;
#pragma unroll
    for (int ks = 0; ks < 4; ++ks) {
        float4 a0 = *(const float4*)(fr + ks * 32 + lg * 8);
        float4 a1 = *(const float4*)(fr + ks * 32 + lg * 8 + 4);
        f16x8 v;
        v[0] = (_Float16)a0.x; v[1] = (_Float16)a0.y;
        v[2] = (_Float16)a0.z; v[3] = (_Float16)a0.w;
        v[4] = (_Float16)a1.x; v[5] = (_Float16)a1.y;
        v[6] = (_Float16)a1.z; v[7] = (_Float16)a1.w;
        af[ks] = v;
    }

#pragma unroll
    for (int ct = 0; ct < 4; ++ct) {
        int col = cb + ct * 16 + lp;
        const _Float16* wrow = Wpq + (size_t)col * 128;
        f32x4 acc = 0.f;
#pragma unroll
        for (int ks = 0; ks < 4; ++ks) {
            f16x8 bf = *(const f16x8*)(wrow + ks * 32 + lg * 8);
            acc = __builtin_amdgcn_mfma_f32_16x16x32_f16(af[ks], bf, acc, 0, 0, 0);
        }
        float b1v = b1e[col];
#pragma unroll
        for (int e = 0; e < 4; ++e)
            T[lg * 4 + e][ct * 16 + lp] = (_Float16)(acc[e] + b1v);
    }
    __syncthreads();

    // coalesced store: 4 lanes per row, 32B each -> 128B/row contiguous
    int r  = lane >> 2;
    int c4 = (lane & 3) * 16;
    uint4 v0 = *(const uint4*)&T[r][c4];
    uint4 v1 = *(const uint4*)&T[r][c4 + 8];
    _Float16* dst = PQ + (size_t)(r0 + r) * 256 + cb + c4;
    *(uint4*)dst       = v0;
    *(uint4*)(dst + 8) = v1;
}

// ---------------- kernel 3: fused pair MLP, flat grid over valid tiles ----------------
// launch_bounds(256,2): 256-reg budget -> all fragments arch-VGPR-resident,
// no v_accvgpr shuttling around MFMAs (the suspected hidden VALU cost).
__global__ __launch_bounds__(256, 2) void pair_mfma_kernel(
        const _Float16* __restrict__ PQ,
        const _Float16* __restrict__ W2h,
        const float* __restrict__ b2p, const _Float16* __restrict__ w3h,
        const float* __restrict__ b3v,
        const int* __restrict__ idx, const int* __restrict__ cnt,
        float* __restrict__ out) {
    int t = blockIdx.x;
    // map flat tile id -> (b, i0, j0) via per-batch tile counts from cnt[]
    int b = -1, local = 0, nv = 0, acc = 0;
#pragma unroll
    for (int k = 0; k < B; ++k) {
        int c   = cnt[k];
        int nTi = (c + IC - 1) / IC;
        int nTj = (c + JT - 1) / JT;
        int tl  = nTi * nTj;
        if (b < 0 && t < acc + tl) { b = k; local = t - acc; nv = c; }
        acc += tl;
    }
    if (b < 0) return;                 // contiguous dead tail
    int nTj = (nv + JT - 1) / JT;
    int i0  = (local / nTj) * IC;
    int j0  = (local % nTj) * JT;

    int tid  = threadIdx.x;
    int lane = tid & 63;
    int w    = tid >> 6;          // wave 0..3
    int lg   = lane >> 4;         // k-slice group 0..3
    int lp   = lane & 15;         // pair col / row-within-group

    __shared__ uint4 Pl[IC][16];  // P rows (compacted) as f16
    __shared__ int   iI[IC];      // original row index per compacted i

    if (tid < IC * 16) {
        int r = tid >> 4, c = tid & 15;
        int ir = i0 + r;
        int ivr = idx[b * N + (ir < nv ? ir : nv - 1)];
        if (c == 0) iI[r] = ivr;
        Pl[r][c] = *(const uint4*)(PQ + ((size_t)(b * N) + ivr) * 256 + c * 8);
    }
    __syncthreads();

    // W2 fragments (permuted rows), register-resident
    F8 w2f[4][4];
#pragma unroll
    for (int g = 0; g < 4; ++g)
#pragma unroll
        for (int c = 0; c < 4; ++c)
            w2f[g][c].u = *(const uint4*)(W2h + (size_t)(g * 16 + lp) * 128 + c * 32 + lg * 8);

    // Q fragments: lane's compacted pair jj = j0 + w*16 + lp
    int jj   = j0 + w * 16 + lp;
    bool jok = jj < nv;
    int jidx = idx[b * N + (jok ? jj : nv - 1)];
    F8 qf[4];
    {
        const _Float16* qrow = PQ + ((size_t)(b * N) + jidx) * 256 + 128;
#pragma unroll
        for (int c = 0; c < 4; ++c)
            qf[c].u = *(const uint4*)(qrow + c * 32 + lg * 8);
    }

    // epilogue constants
    f32x4 b2v[4];
#pragma unroll
    for (int g = 0; g < 4; ++g)
        b2v[g] = *(const f32x4*)(b2p + g * 16 + lg * 4);
    f16x8 w3f0 = *(const f16x8*)(w3h + lg * 8);
    f16x8 w3f1 = *(const f16x8*)(w3h + 32 + lg * 8);
    float b3s = b3v[0];
    const f32x4 z4 = 0.f;
    const f16x8 zh = (f16x8)(_Float16)0;

    size_t outbase = ((size_t)(b * N)) * N;

#define COMPUTE(ACC, II)                                                       \
    {                                                                          \
        _Pragma("unroll")                                                      \
        for (int g = 0; g < 4; ++g) ACC[g] = 0.f;                              \
        _Pragma("unroll")                                                      \
        for (int c = 0; c < 4; ++c) {                                          \
            F8 ph; ph.u = Pl[II][c * 4 + lg];                                  \
            f16x8 hv = __builtin_elementwise_max(ph.f + qf[c].f, zh);          \
            _Pragma("unroll")                                                  \
            for (int g = 0; g < 4; ++g)                                        \
                ACC[g] = __builtin_amdgcn_mfma_f32_16x16x32_f16(               \
                    w2f[g][c].f, hv, ACC[g], 0, 0, 0);                         \
        }                                                                      \
    }

#define EPI(ACC, II)                                                           \
    {                                                                          \
        f32x4 t0 = __builtin_elementwise_max(ACC[0] + b2v[0], z4);             \
        f32x4 t1 = __builtin_elementwise_max(ACC[1] + b2v[1], z4);             \
        f32x4 t2 = __builtin_elementwise_max(ACC[2] + b2v[2], z4);             \
        f32x4 t3 = __builtin_elementwise_max(ACC[3] + b2v[3], z4);             \
        f16x8 h0, h1;                                                          \
        h0[0] = (_Float16)t0[0]; h0[1] = (_Float16)t0[1];                      \
        h0[2] = (_Float16)t0[2]; h0[3] = (_Float16)t0[3];                      \
        h0[4] = (_Float16)t1[0]; h0[5] = (_Float16)t1[1];                      \
        h0[6] = (_Float16)t1[2]; h0[7] = (_Float16)t1[3];                      \
        h1[0] = (_Float16)t2[0]; h1[1] = (_Float16)t2[1];                      \
        h1[2] = (_Float16)t2[2]; h1[3] = (_Float16)t2[3];                      \
        h1[4] = (_Float16)t3[0]; h1[5] = (_Float16)t3[1];                      \
        h1[6] = (_Float16)t3[2]; h1[7] = (_Float16)t3[3];                      \
        f32x4 rac = {b3s, b3s, b3s, b3s};                                      \
        rac = __builtin_amdgcn_mfma_f32_16x16x32_f16(w3f0, h0, rac, 0, 0, 0);  \
        rac = __builtin_amdgcn_mfma_f32_16x16x32_f16(w3f1, h1, rac, 0, 0, 0);  \
        float val = 1.f / (1.f + __expf(-rac[0]));                             \
        if (lane < 16 && jok && (i0 + (II)) < nv)                              \
            out[outbase + (size_t)iI[II] * N + jidx] = val;                    \
    }

    f32x4 accA[4], accB[4];
#pragma unroll 1
    for (int ii = 0; ii < IC; ii += 2) {
        COMPUTE(accA, ii)
        COMPUTE(accB, ii + 1)
        EPI(accA, ii)
        EPI(accB, ii + 1)
    }

#undef COMPUTE
#undef EPI
}

extern "C" void kernel_launch(void* const* d_in, const int* in_sizes, int n_in,
                              void* d_out, int out_size, void* d_ws, size_t ws_size,
                              hipStream_t stream) {
    const float* F0  = (const float*)d_in[0];
    const int*   msk = (const int*)  d_in[1];
    const float* W1  = (const float*)d_in[2];
    const float* b1  = (const float*)d_in[3];
    const float* W2  = (const float*)d_in[4];
    const float* b2  = (const float*)d_in[5];
    const float* W3  = (const float*)d_in[6];
    const float* b3  = (const float*)d_in[7];
    float* out = (float*)d_out;

    char* ws = (char*)d_ws;
    _Float16* PQ  = (_Float16*)ws;                                   // 2 MB
    _Float16* Wpq = (_Float16*)(ws + (2u << 20));                    // 64 KB
    _Float16* W2h = (_Float16*)(ws + (2u << 20) + (64u << 10));      // 16 KB
    float*    b1e = (float*)   (ws + (2u << 20) + (80u << 10));      // 1 KB
    float*    b2p = (float*)   (ws + (2u << 20) + (81u << 10));      // 256 B
    _Float16* w3h = (_Float16*)(ws + (2u << 20) + (82u << 10));      // 128 B
    int*      idx = (int*)     (ws + (2u << 20) + (84u << 10));      // 16 KB
    int*      cnt = (int*)     (ws + (2u << 20) + (100u << 10));     // 64 B

    // masked pairs output sigmoid(-1e9) == 0.0f exactly -> zero-fill output
    int n4 = (B * N * N) / 4;     // 524288 float4s
    fill0_kernel<<<(n4 + 255) / 256, 256, 0, stream>>>((float4*)out, n4);

    build_w_kernel<<<64, 256, 0, stream>>>(W1, W2, b1, b2, W3, Wpq, W2h, b1e, b2p, w3h);
    scan_kernel<<<B, 64, 0, stream>>>(msk, idx, cnt);
    pq_mfma_kernel<<<dim3(B * N / 16, 4), 64, 0, stream>>>(F0, Wpq, b1e, PQ);

    int maxTiles = B * ((N + IC - 1) / IC) * ((N + JT - 1) / JT);    // 4096
    pair_mfma_kernel<<<maxTiles, 256, 0, stream>>>(
        PQ, W2h, b2p, w3h, b3, idx, cnt, out);
}

// Round 16
// 34.870 us; speedup vs baseline: 4.0924x; 1.2000x over previous
//
#include <hip/hip_runtime.h>

#define B 8
#define N 512
#define D 128
#define H 128
#define IC 8      // valid-i rows per block (pair kernel)
#define JT 64     // valid-j cols per block (4 waves x 16)

typedef __attribute__((ext_vector_type(8))) _Float16 f16x8;
typedef __attribute__((ext_vector_type(4))) float f32x4;

union F8 { uint4 u; f16x8 f; };

// W2-row permutation for the reduce-MFMA epilogue:
// pi(g,m) = (g>=2)*32 + (m>>2)*8 + (g&1)*4 + (m&3)
__device__ __host__ inline int w2perm(int g, int m) {
    return ((g >> 1) << 5) + ((m >> 2) << 3) + ((g & 1) << 2) + (m & 3);
}

// ---------------- kernel F: fast zero-fill of the output ----------------
__global__ __launch_bounds__(256) void fill0_kernel(float4* __restrict__ out, int n4) {
    int i = blockIdx.x * blockDim.x + threadIdx.x;
    if (i < n4) out[i] = float4{0.f, 0.f, 0.f, 0.f};
}

// ---------------- kernel 0: build weights (blocks 0-63) + scan (blocks 64-71) ----------------
__global__ __launch_bounds__(256) void build_scan_kernel(
        const float* __restrict__ W1, const float* __restrict__ W2,
        const float* __restrict__ b1, const float* __restrict__ b2,
        const float* __restrict__ W3, const int* __restrict__ mask,
        _Float16* __restrict__ Wpq, _Float16* __restrict__ W2h,
        float* __restrict__ b1e, float* __restrict__ b2p,
        _Float16* __restrict__ w3h,
        int* __restrict__ idx, int* __restrict__ cnt) {
    int blk = blockIdx.x;
    if (blk < 64) {
        int t = blk * 256 + threadIdx.x;   // 0 .. 16383
        if (t < H * D) {
            int h = t >> 7, k = t & 127;
            float wa = W1[h * 384 + k];
            float wb = W1[h * 384 + 128 + k];
            float wc = W1[h * 384 + 256 + k];
            Wpq[h * 128 + k]         = (_Float16)(wa + wc);
            Wpq[(128 + h) * 128 + k] = (_Float16)(wb - wc);
        }
        if (t < 64 * H) {   // permuted W2 rows
            int on = t >> 7, k = t & 127;
            int pi = w2perm(on >> 4, on & 15);
            W2h[t] = (_Float16)W2[pi * 128 + k];
        }
        if (t < 256) b1e[t] = (t < 128) ? b1[t] : 0.f;
        if (t < 64) {
            int pi = w2perm(t >> 4, t & 15);
            b2p[t] = b2[pi];
            w3h[t] = (_Float16)W3[t];
        }
    } else {
        int b = blk - 64;
        int lane = threadIdx.x;
        if (lane >= 64) return;
        const int* m = mask + b * N;
        int base = 0;
        for (int ch = 0; ch < N / 64; ++ch) {
            int v = m[ch * 64 + lane];
            unsigned long long bal = __ballot(v != 0);
            int pos = base + __popcll(bal & ((1ull << lane) - 1ull));
            if (v) idx[b * N + pos] = ch * 64 + lane;
            base += __popcll(bal);
        }
        if (lane == 0) cnt[b] = base;
    }
}

// ---------------- kernel 2: PQ = f16( F0 @ Wpq^T + b1e ), coalesced stores ----------------
__global__ __launch_bounds__(64) void pq_mfma_kernel(const float* __restrict__ F0,
                                                     const _Float16* __restrict__ Wpq,
                                                     const float* __restrict__ b1e,
                                                     _Float16* __restrict__ PQ) {
    int r0 = blockIdx.x * 16;        // F0 row base
    int cb = blockIdx.y * 64;        // output col base
    int lane = threadIdx.x;
    int lp = lane & 15, lg = lane >> 4;

    __shared__ _Float16 T[16][64];   // 2 KB transpose staging

    f16x8 af[4];
    const float* fr = F0 + (size_t)(r0 + lp) * D;
#pragma unroll
    for (int ks = 0; ks < 4; ++ks) {
        float4 a0 = *(const float4*)(fr + ks * 32 + lg * 8);
        float4 a1 = *(const float4*)(fr + ks * 32 + lg * 8 + 4);
        f16x8 v;
        v[0] = (_Float16)a0.x; v[1] = (_Float16)a0.y;
        v[2] = (_Float16)a0.z; v[3] = (_Float16)a0.w;
        v[4] = (_Float16)a1.x; v[5] = (_Float16)a1.y;
        v[6] = (_Float16)a1.z; v[7] = (_Float16)a1.w;
        af[ks] = v;
    }

#pragma unroll
    for (int ct = 0; ct < 4; ++ct) {
        int col = cb + ct * 16 + lp;
        const _Float16* wrow = Wpq + (size_t)col * 128;
        f32x4 acc = 0.f;
#pragma unroll
        for (int ks = 0; ks < 4; ++ks) {
            f16x8 bf = *(const f16x8*)(wrow + ks * 32 + lg * 8);
            acc = __builtin_amdgcn_mfma_f32_16x16x32_f16(af[ks], bf, acc, 0, 0, 0);
        }
        float b1v = b1e[col];
#pragma unroll
        for (int e = 0; e < 4; ++e)
            T[lg * 4 + e][ct * 16 + lp] = (_Float16)(acc[e] + b1v);
    }
    __syncthreads();

    // coalesced store: 4 lanes per row, 32B each -> 128B/row contiguous
    int r  = lane >> 2;
    int c4 = (lane & 3) * 16;
    uint4 v0 = *(const uint4*)&T[r][c4];
    uint4 v1 = *(const uint4*)&T[r][c4 + 8];
    _Float16* dst = PQ + (size_t)(r0 + r) * 256 + cb + c4;
    *(uint4*)dst       = v0;
    *(uint4*)(dst + 8) = v1;
}

// ---------------- kernel 3: fused pair MLP; W2 in swizzled LDS ----------------
// w2f regs (64 VGPR) -> LDS with unit-XOR swizzle (free 2-way bank aliasing);
// launch_bounds(256,3) -> 3+ waves/SIMD to cover the per-wave latency chain.
__global__ __launch_bounds__(256, 3) void pair_mfma_kernel(
        const _Float16* __restrict__ PQ,
        const _Float16* __restrict__ W2h,
        const float* __restrict__ b2p, const _Float16* __restrict__ w3h,
        const float* __restrict__ b3v,
        const int* __restrict__ idx, const int* __restrict__ cnt,
        float* __restrict__ out) {
    int t = blockIdx.x;
    // map flat tile id -> (b, i0, j0) via per-batch tile counts from cnt[]
    int b = -1, local = 0, nv = 0, acc = 0;
#pragma unroll
    for (int k = 0; k < B; ++k) {
        int c   = cnt[k];
        int nTi = (c + IC - 1) / IC;
        int nTj = (c + JT - 1) / JT;
        int tl  = nTi * nTj;
        if (b < 0 && t < acc + tl) { b = k; local = t - acc; nv = c; }
        acc += tl;
    }
    if (b < 0) return;                 // contiguous dead tail
    int nTj = (nv + JT - 1) / JT;
    int i0  = (local / nTj) * IC;
    int j0  = (local % nTj) * JT;

    int tid  = threadIdx.x;
    int lane = tid & 63;
    int w    = tid >> 6;          // wave 0..3
    int lg   = lane >> 4;         // k-slice group 0..3
    int lp   = lane & 15;         // pair col / row-within-group

    __shared__ uint4 W2s[64][16]; // 16 KB, unit-swizzled: [row][u ^ (row&15)]
    __shared__ uint4 Pl[IC][16];  // P rows (compacted) as f16
    __shared__ int   iI[IC];      // original row index per compacted i

    {   // stage W2 (1024 uint4), coalesced global read, swizzled LDS write
        const uint4* W2v = (const uint4*)W2h;
#pragma unroll
        for (int q = 0; q < 4; ++q) {
            int m = tid + q * 256;
            int r = m >> 4, u = m & 15;
            W2s[r][u ^ (r & 15)] = W2v[m];
        }
    }
    if (tid < IC * 16) {
        int r = tid >> 4, c = tid & 15;
        int ir = i0 + r;
        int ivr = idx[b * N + (ir < nv ? ir : nv - 1)];
        if (c == 0) iI[r] = ivr;
        Pl[r][c] = *(const uint4*)(PQ + ((size_t)(b * N) + ivr) * 256 + c * 8);
    }
    __syncthreads();

    // per-c W2 read pointers: row = g*16+lp, unit = (c*4+lg)^lp; g via +g*256 units
    const uint4* pw0 = &W2s[lp][(0 * 4 + lg) ^ lp];
    const uint4* pw1 = &W2s[lp][(1 * 4 + lg) ^ lp];
    const uint4* pw2 = &W2s[lp][(2 * 4 + lg) ^ lp];
    const uint4* pw3 = &W2s[lp][(3 * 4 + lg) ^ lp];

    // Q fragments: lane's compacted pair jj = j0 + w*16 + lp
    int jj   = j0 + w * 16 + lp;
    bool jok = jj < nv;
    int jidx = idx[b * N + (jok ? jj : nv - 1)];
    F8 qf[4];
    {
        const _Float16* qrow = PQ + ((size_t)(b * N) + jidx) * 256 + 128;
#pragma unroll
        for (int c = 0; c < 4; ++c)
            qf[c].u = *(const uint4*)(qrow + c * 32 + lg * 8);
    }

    // epilogue constants
    f32x4 b2v[4];
#pragma unroll
    for (int g = 0; g < 4; ++g)
        b2v[g] = *(const f32x4*)(b2p + g * 16 + lg * 4);
    f16x8 w3f0 = *(const f16x8*)(w3h + lg * 8);
    f16x8 w3f1 = *(const f16x8*)(w3h + 32 + lg * 8);
    float b3s = b3v[0];
    const f32x4 z4 = 0.f;
    const f16x8 zh = (f16x8)(_Float16)0;

    size_t outbase = ((size_t)(b * N)) * N;

#define CSTEP(ACC, II, C, PW)                                                  \
    {                                                                          \
        F8 ph; ph.u = Pl[II][(C) * 4 + lg];                                    \
        f16x8 hv = __builtin_elementwise_max(ph.f + qf[C].f, zh);              \
        F8 a0, a1, a2, a3;                                                     \
        a0.u = PW[0 * 256]; a1.u = PW[1 * 256];                                \
        a2.u = PW[2 * 256]; a3.u = PW[3 * 256];                                \
        ACC[0] = __builtin_amdgcn_mfma_f32_16x16x32_f16(a0.f, hv, ACC[0], 0, 0, 0); \
        ACC[1] = __builtin_amdgcn_mfma_f32_16x16x32_f16(a1.f, hv, ACC[1], 0, 0, 0); \
        ACC[2] = __builtin_amdgcn_mfma_f32_16x16x32_f16(a2.f, hv, ACC[2], 0, 0, 0); \
        ACC[3] = __builtin_amdgcn_mfma_f32_16x16x32_f16(a3.f, hv, ACC[3], 0, 0, 0); \
    }

#define COMPUTE(ACC, II)                                                       \
    {                                                                          \
        _Pragma("unroll")                                                      \
        for (int g = 0; g < 4; ++g) ACC[g] = 0.f;                              \
        CSTEP(ACC, II, 0, pw0)                                                 \
        CSTEP(ACC, II, 1, pw1)                                                 \
        CSTEP(ACC, II, 2, pw2)                                                 \
        CSTEP(ACC, II, 3, pw3)                                                 \
    }

#define EPI(ACC, II)                                                           \
    {                                                                          \
        f32x4 t0 = __builtin_elementwise_max(ACC[0] + b2v[0], z4);             \
        f32x4 t1 = __builtin_elementwise_max(ACC[1] + b2v[1], z4);             \
        f32x4 t2 = __builtin_elementwise_max(ACC[2] + b2v[2], z4);             \
        f32x4 t3 = __builtin_elementwise_max(ACC[3] + b2v[3], z4);             \
        f16x8 h0, h1;                                                          \
        h0[0] = (_Float16)t0[0]; h0[1] = (_Float16)t0[1];                      \
        h0[2] = (_Float16)t0[2]; h0[3] = (_Float16)t0[3];                      \
        h0[4] = (_Float16)t1[0]; h0[5] = (_Float16)t1[1];                      \
        h0[6] = (_Float16)t1[2]; h0[7] = (_Float16)t1[3];                      \
        h1[0] = (_Float16)t2[0]; h1[1] = (_Float16)t2[1];                      \
        h1[2] = (_Float16)t2[2]; h1[3] = (_Float16)t2[3];                      \
        h1[4] = (_Float16)t3[0]; h1[5] = (_Float16)t3[1];                      \
        h1[6] = (_Float16)t3[2]; h1[7] = (_Float16)t3[3];                      \
        f32x4 rac = {b3s, b3s, b3s, b3s};                                      \
        rac = __builtin_amdgcn_mfma_f32_16x16x32_f16(w3f0, h0, rac, 0, 0, 0);  \
        rac = __builtin_amdgcn_mfma_f32_16x16x32_f16(w3f1, h1, rac, 0, 0, 0);  \
        float val = 1.f / (1.f + __expf(-rac[0]));                             \
        if (lane < 16 && jok && (i0 + (II)) < nv)                              \
            out[outbase + (size_t)iI[II] * N + jidx] = val;                    \
    }

    f32x4 accA[4], accB[4];
#pragma unroll 1
    for (int ii = 0; ii < IC; ii += 2) {
        COMPUTE(accA, ii)
        COMPUTE(accB, ii + 1)
        EPI(accA, ii)
        EPI(accB, ii + 1)
    }

#undef CSTEP
#undef COMPUTE
#undef EPI
}

extern "C" void kernel_launch(void* const* d_in, const int* in_sizes, int n_in,
                              void* d_out, int out_size, void* d_ws, size_t ws_size,
                              hipStream_t stream) {
    const float* F0  = (const float*)d_in[0];
    const int*   msk = (const int*)  d_in[1];
    const float* W1  = (const float*)d_in[2];
    const float* b1  = (const float*)d_in[3];
    const float* W2  = (const float*)d_in[4];
    const float* b2  = (const float*)d_in[5];
    const float* W3  = (const float*)d_in[6];
    const float* b3  = (const float*)d_in[7];
    float* out = (float*)d_out;

    char* ws = (char*)d_ws;
    _Float16* PQ  = (_Float16*)ws;                                   // 2 MB
    _Float16* Wpq = (_Float16*)(ws + (2u << 20));                    // 64 KB
    _Float16* W2h = (_Float16*)(ws + (2u << 20) + (64u << 10));      // 16 KB
    float*    b1e = (float*)   (ws + (2u << 20) + (80u << 10));      // 1 KB
    float*    b2p = (float*)   (ws + (2u << 20) + (81u << 10));      // 256 B
    _Float16* w3h = (_Float16*)(ws + (2u << 20) + (82u << 10));      // 128 B
    int*      idx = (int*)     (ws + (2u << 20) + (84u << 10));      // 16 KB
    int*      cnt = (int*)     (ws + (2u << 20) + (100u << 10));     // 64 B

    // masked pairs output sigmoid(-1e9) == 0.0f exactly -> zero-fill output
    int n4 = (B * N * N) / 4;     // 524288 float4s
    fill0_kernel<<<(n4 + 255) / 256, 256, 0, stream>>>((float4*)out, n4);

    build_scan_kernel<<<72, 256, 0, stream>>>(W1, W2, b1, b2, W3, msk,
                                              Wpq, W2h, b1e, b2p, w3h, idx, cnt);
    pq_mfma_kernel<<<dim3(B * N / 16, 4), 64, 0, stream>>>(F0, Wpq, b1e, PQ);

    int maxTiles = B * ((N + IC - 1) / IC) * ((N + JT - 1) / JT);    // 4096
    pair_mfma_kernel<<<maxTiles, 256, 0, stream>>>(
        PQ, W2h, b2p, w3h, b3, idx, cnt, out);
}